// Round 8
// baseline (863.143 us; speedup 1.0000x reference)
//
#include <hip/hip_runtime.h>

typedef unsigned short u16;
typedef unsigned int u32;
typedef __attribute__((ext_vector_type(4))) float f32x4;
typedef __attribute__((ext_vector_type(8))) short bf16x8;
typedef __attribute__((ext_vector_type(4))) short bf16x4;
typedef __attribute__((ext_vector_type(4))) u16 u16x4;

#define N_NODES 16384
#define N_EDGES 8192
#define FK_SCALE 0.17677669529663687f
#define LOG2E 1.4426950408889634f
#define C1EXP (FK_SCALE * LOG2E)
#define NSPLIT 3

typedef const u32 __attribute__((address_space(1))) gu32;
typedef u32 __attribute__((address_space(3))) lu32;

__device__ __forceinline__ void gl_lds16(const void* g, void* l) {
  __builtin_amdgcn_global_load_lds((gu32*)g, (lu32*)l, 16, 0, 0);
}

__device__ __forceinline__ float b2f(u16 u) {
  return __builtin_bit_cast(float, (u32)u << 16);
}
__device__ __forceinline__ u16 f2b(float f) {
  u32 u = __builtin_bit_cast(u32, f);
  u += 0x7fffu + ((u >> 16) & 1u);
  return (u16)(u >> 16);
}

// ---------------- X -> bf16 ----------------
__global__ __launch_bounds__(256) void k_cvt(const float* __restrict__ X,
                                             u16* __restrict__ Xb) {
  int i = blockIdx.x * 256 + threadIdx.x;
  f32x4 v = *(const f32x4*)(X + i * 4);
  u16x4 r;
  r.x = f2b(v.x); r.y = f2b(v.y); r.z = f2b(v.z); r.w = f2b(v.w);
  *(u16x4*)(Xb + i * 4) = r;
}

// ---------------- W transpose+cvt (coalesced via LDS) ----------------
__global__ __launch_bounds__(256) void k_wt(const float* __restrict__ Wq,
                                            const float* __restrict__ Wk,
                                            const float* __restrict__ Wv,
                                            const float* __restrict__ Wke,
                                            u16* __restrict__ Wt) {
  __shared__ float tile[64][65];
  int w = blockIdx.z;
  const float* W = (w == 0) ? Wq : (w == 1) ? Wk : (w == 2) ? Wv : Wke;
  int k0 = blockIdx.x * 64, n0 = blockIdx.y * 64;
  int tid = threadIdx.x;
#pragma unroll
  for (int i = 0; i < 16; i++) {
    int idx = i * 256 + tid;
    int kr = idx >> 6, nc = idx & 63;
    tile[nc][kr] = W[(k0 + kr) * 256 + n0 + nc];
  }
  __syncthreads();
#pragma unroll
  for (int i = 0; i < 16; i++) {
    int idx = i * 256 + tid;
    int nr = idx >> 6, kc = idx & 63;
    Wt[w * 65536 + (n0 + nr) * 256 + k0 + kc] = f2b(tile[nr][kc]);
  }
}

// ---------------- bias pack ----------------
__global__ __launch_bounds__(256) void k_bias(const float* __restrict__ bq,
                                              const float* __restrict__ bk,
                                              const float* __restrict__ bv,
                                              const float* __restrict__ bke,
                                              float* __restrict__ bcat) {
  int i = blockIdx.x * 256 + threadIdx.x;
  float v;
  if (i < 256) v = bq[i];
  else if (i < 512) v = bk[i - 256];
  else if (i < 768) v = bv[i - 512];
  else v = bke[i - 768];
  bcat[i] = v;
}

// ---------------- histogram of e_ids ----------------
__global__ __launch_bounds__(256) void k_hist(const int* __restrict__ e_ids,
                                              int* __restrict__ hist) {
  int base = blockIdx.x * 1024 + threadIdx.x;
#pragma unroll
  for (int k = 0; k < 4; k++) atomicAdd(&hist[e_ids[base + k * 256]], 1);
}

// ---------------- exclusive scan (1 block) ----------------
__global__ __launch_bounds__(256) void k_scan(const int* __restrict__ hist,
                                              int* __restrict__ eoff,
                                              int* __restrict__ cur) {
  __shared__ int ts[256];
  int t = threadIdx.x;
  int base = t * 32;
  int vals[32];
  int s = 0;
#pragma unroll
  for (int i = 0; i < 32; i++) { vals[i] = hist[base + i]; s += vals[i]; }
  ts[t] = s;
  __syncthreads();
  for (int off = 1; off < 256; off <<= 1) {
    int v = (t >= off) ? ts[t - off] : 0;
    __syncthreads();
    ts[t] += v;
    __syncthreads();
  }
  int ex = ts[t] - s;
#pragma unroll
  for (int i = 0; i < 32; i++) {
    eoff[base + i] = ex;
    cur[base + i] = ex;
    ex += vals[i];
  }
  if (t == 255) eoff[8192] = ex;
}

// ---------------- permute ----------------
__global__ __launch_bounds__(256) void k_perm(const int* __restrict__ v_ids,
                                              const int* __restrict__ e_ids,
                                              int* __restrict__ cur,
                                              int* __restrict__ perm) {
  int base = blockIdx.x * 1024 + threadIdx.x;
#pragma unroll
  for (int k = 0; k < 4; k++) {
    int i = base + k * 256;
    int e = e_ids[i];
    int v = v_ids[i];
    int pos = atomicAdd(&cur[e], 1);
    perm[pos] = v;
  }
}

// ---------------- per-edge gather-mean ----------------
__global__ __launch_bounds__(256) void k_gather(const u16* __restrict__ Xb,
                                                const int* __restrict__ perm,
                                                const int* __restrict__ eoff,
                                                u16* __restrict__ Xe) {
  __shared__ float red[4][256];
  int e = blockIdx.x;
  int tid = threadIdx.x, wave = tid >> 6, lane = tid & 63;
  int start = eoff[e], end = eoff[e + 1];
  f32x4 acc = {0.f, 0.f, 0.f, 0.f};
  for (int j = start + wave; j < end; j += 4) {
    int v = perm[j];
    bf16x4 x = *(const bf16x4*)(Xb + v * 256 + lane * 4);
#pragma unroll
    for (int c = 0; c < 4; c++) acc[c] += b2f((u16)x[c]);
  }
  *(f32x4*)&red[wave][lane * 4] = acc;
  __syncthreads();
  int t = tid;
  float s = red[0][t] + red[1][t] + red[2][t] + red[3][t];
  float m = s / fmaxf((float)(end - start), 1.0f);
  Xe[e * 256 + t] = f2b(m);
}

// ---------------- transpose Xe -> XeT ----------------
__global__ __launch_bounds__(256) void k_xt(const u16* __restrict__ Xe,
                                            u16* __restrict__ XeT) {
  __shared__ u16 tile[64][65];
  int e0 = blockIdx.x * 64, c0 = blockIdx.y * 64;
  int tid = threadIdx.x;
#pragma unroll
  for (int i = 0; i < 16; i++) {
    int idx = i * 256 + tid;
    int er = idx >> 6, cr = idx & 63;
    tile[cr][er] = Xe[(e0 + er) * 256 + c0 + cr];
  }
  __syncthreads();
#pragma unroll
  for (int i = 0; i < 16; i++) {
    int idx = i * 256 + tid;
    int cr = idx >> 6, er = idx & 63;
    XeT[(c0 + cr) * 8192 + e0 + er] = tile[cr][er];
  }
}

// ---------------- GEMM 64x64, K=256 ----------------
__global__ __launch_bounds__(256) void k_gemm64(const u16* __restrict__ A,
                                                const u16* __restrict__ Wt,
                                                const float* __restrict__ bias,
                                                u16* __restrict__ out,
                                                int ldout) {
  __shared__ u16 As[64 * 256];
  __shared__ u16 Bs[64 * 256];
  int tid = threadIdx.x;
  int mtile = blockIdx.x * 64;
  int gn = blockIdx.y * 64;
  const u16* Ap = A + mtile * 256;
  const u16* Bp = Wt + gn * 256;
#pragma unroll
  for (int i = 0; i < 8; i++) {
    gl_lds16(Ap + i * 2048 + tid * 8, As + i * 2048 + tid * 8);
    gl_lds16(Bp + i * 2048 + tid * 8, Bs + i * 2048 + tid * 8);
  }
  __syncthreads();
  int wave = tid >> 6, lane = tid & 63;
  int quad = lane >> 4, l16 = lane & 15;
  bf16x8 a[8];
#pragma unroll
  for (int kc = 0; kc < 8; kc++)
    a[kc] = *(const bf16x8*)(As + (wave * 16 + l16) * 256 + kc * 32 + quad * 8);
#pragma unroll
  for (int nt = 0; nt < 4; nt++) {
    f32x4 acc = {0.f, 0.f, 0.f, 0.f};
#pragma unroll
    for (int kc = 0; kc < 8; kc++) {
      bf16x8 b = *(const bf16x8*)(Bs + (nt * 16 + l16) * 256 + kc * 32 + quad * 8);
      acc = __builtin_amdgcn_mfma_f32_16x16x32_bf16(a[kc], b, acc, 0, 0, 0);
    }
#pragma unroll
    for (int r = 0; r < 4; r++) {
      int row = mtile + wave * 16 + quad * 4 + r;
      int col = gn + nt * 16 + l16;
      out[row * ldout + col] = f2b(acc[r] + bias[col]);
    }
  }
}

// ---------------- kappa = max_e ||Ke_e||^2 (256 atomics total) ----------------
__global__ __launch_bounds__(256) void k_knorm(const u16* __restrict__ Keb,
                                               float* __restrict__ kappa) {
  __shared__ float red[4];
  int tid = threadIdx.x;
  int wave = tid >> 6, lane = tid & 63;
  float mx = 0.f;
#pragma unroll
  for (int i = 0; i < 8; i++) {
    int e = blockIdx.x * 32 + wave * 8 + i;
    bf16x4 x = *(const bf16x4*)(Keb + e * 256 + lane * 4);
    float s = 0.f;
#pragma unroll
    for (int c = 0; c < 4; c++) { float v = b2f((u16)x[c]); s += v * v; }
#pragma unroll
    for (int off = 1; off < 64; off <<= 1) s += __shfl_xor(s, off, 64);
    mx = fmaxf(mx, s);
  }
  if (lane == 0) red[wave] = mx;
  __syncthreads();
  if (tid == 0) {
    float m = fmaxf(fmaxf(red[0], red[1]), fmaxf(red[2], red[3]));
    atomicMax((int*)kappa, __float_as_int(m));  // all values >= 0
  }
}

// ---------------- M2row[n] = ||Qe_n|| * sqrt(kappa) * scale * log2e ----------------
__global__ __launch_bounds__(256) void k_qnorm(const u16* __restrict__ QKV,
                                               const float* __restrict__ kappa,
                                               float* __restrict__ M2row) {
  int tid = threadIdx.x;
  int wave = tid >> 6, lane = tid & 63;
  int n = blockIdx.x * 4 + wave;
  bf16x4 x = *(const bf16x4*)(QKV + n * 768 + lane * 4);
  float s = 0.f;
#pragma unroll
  for (int c = 0; c < 4; c++) { float v = b2f((u16)x[c]); s += v * v; }
#pragma unroll
  for (int off = 1; off < 64; off <<= 1) s += __shfl_xor(s, off, 64);
  if (lane == 0) M2row[n] = sqrtf(s * kappa[0]) * C1EXP;
}

// ---------------- flash partial: K from global(L2), V+P in LDS ----------------
// 768 blocks = 256 q-tiles x 3 splits; 4 waves; Bq=16/wave; Bk=64.
// LDS 40 KB: VL [256][64] swz-8 (32K) | PL [4][16][64] swz-8 (8K).
// launch_bounds(256,3) -> 3 blocks/CU (120 KB LDS), 170 unified regs/wave.
// Per wave-iter: 34 ds_read_b128 (halved vs R6), 32 global K-frag loads (L2),
// 64 MFMA. Barrier drains overlap across 3 co-resident blocks.
__global__ __launch_bounds__(256, 3) void k_flash(const u16* __restrict__ QKV,
                                                  const u16* __restrict__ Keb,
                                                  const u16* __restrict__ XeT,
                                                  const float* __restrict__ M2row,
                                                  u16* __restrict__ Op,
                                                  float* __restrict__ Lv) {
  extern __shared__ u16 sm[];
  u16* VL = sm;                // [256][64] swizzled (XOR-8, 128-B rows)
  u16* PL = sm + 16384;        // [4][16][64] swizzled
  int tid = threadIdx.x;
  int wave = tid >> 6, lane = tid & 63;
  int quad = lane >> 4, l16 = lane & 15;
  int qt = blockIdx.x & 255;
  int split = blockIdx.x >> 8;
  int row0 = qt * 64 + wave * 16;
  u16* PLw = PL + (wave << 10);

  // Q fragments (1 m-tile / wave)
  bf16x8 qf[8];
#pragma unroll
  for (int kc = 0; kc < 8; kc++)
    qf[kc] = *(const bf16x8*)(QKV + (row0 + l16) * 768 + kc * 32 + quad * 8);

  float mb[4];
#pragma unroll
  for (int r = 0; r < 4; r++) mb[r] = M2row[row0 + quad * 4 + r];

  f32x4 o[16];
#pragma unroll
  for (int i = 0; i < 16; i++) o[i] = (f32x4){0.f, 0.f, 0.f, 0.f};
  float l[4] = {0.f, 0.f, 0.f, 0.f};

  int t0 = (split * 128) / 3, t1 = ((split + 1) * 128) / 3;  // 42/43/43 tiles

  for (int kt = t0; kt < t1; kt++) {
    int kbase = kt * 64;
    __syncthreads();  // prev tile fully consumed
    // stage V tile: VL[c][64 keys], 2048 chunk slots, XOR-8 swizzle
#pragma unroll
    for (int i = 0; i < 8; i++) {
      int s = i * 256 + tid;
      int c = s >> 3, p = s & 7;
      int k8 = p ^ (c & 7);
      gl_lds16(XeT + c * 8192 + kbase + k8 * 8, VL + s * 8);
    }
    __syncthreads();  // V resident

    // QK^T: K-fragments straight from L2-resident Keb
#pragma unroll
    for (int nt = 0; nt < 4; nt++) {
      const u16* kr = Keb + (kbase + nt * 16 + l16) * 256 + quad * 8;
      bf16x8 kb[8];
#pragma unroll
      for (int kc = 0; kc < 8; kc++) kb[kc] = *(const bf16x8*)(kr + kc * 32);
      f32x4 a = {0.f, 0.f, 0.f, 0.f};
#pragma unroll
      for (int kc = 0; kc < 8; kc++)
        a = __builtin_amdgcn_mfma_f32_16x16x32_bf16(qf[kc], kb[kc], a, 0, 0, 0);
      int col = nt * 16 + l16;
#pragma unroll
      for (int r = 0; r < 4; r++) {
        float pv = __builtin_amdgcn_exp2f(a[r] * C1EXP - mb[r]);
        l[r] += pv;
        int row = quad * 4 + r;
        PLw[row * 64 + (((col >> 3) ^ (row & 7)) << 3) + (col & 7)] = f2b(pv);
      }
    }
    // P A-fragments (same-wave LDS round trip, no barrier)
    bf16x8 pf[2];
#pragma unroll
    for (int kc2 = 0; kc2 < 2; kc2++) {
      int ck = kc2 * 4 + quad;
      pf[kc2] = *(const bf16x8*)(PLw + l16 * 64 + ((ck ^ (l16 & 7)) << 3));
    }
    // PV
#pragma unroll
    for (int ct = 0; ct < 16; ct++) {
#pragma unroll
      for (int kc2 = 0; kc2 < 2; kc2++) {
        int rv = ct * 16 + l16;
        int ck = kc2 * 4 + quad;
        bf16x8 vb = *(const bf16x8*)(VL + rv * 64 + ((ck ^ (rv & 7)) << 3));
        o[ct] = __builtin_amdgcn_mfma_f32_16x16x32_bf16(pf[kc2], vb, o[ct], 0, 0, 0);
      }
    }
  }

  // reduce row-sums across the 16 lanes of each row
#pragma unroll
  for (int off = 1; off < 16; off <<= 1)
#pragma unroll
    for (int r = 0; r < 4; r++) l[r] += __shfl_xor(l[r], off, 64);

  size_t obase = (size_t)split * N_NODES * 256;
#pragma unroll
  for (int ct = 0; ct < 16; ct++)
#pragma unroll
    for (int r = 0; r < 4; r++) {
      int row = row0 + quad * 4 + r;
      int col = ct * 16 + l16;
      Op[obase + (size_t)row * 256 + col] = f2b(o[ct][r]);
    }
  if (l16 == 0) {
#pragma unroll
    for (int r = 0; r < 4; r++)
      Lv[split * N_NODES + row0 + quad * 4 + r] = l[r];
  }
}

// ---------------- fused: node 8x8 head attention + split combine + ReLU ----------------
__global__ __launch_bounds__(256) void k_comb(const u16* __restrict__ QKV,
                                              const u16* __restrict__ Op,
                                              const float* __restrict__ Lv,
                                              float* __restrict__ out) {
  int idx = blockIdx.x * 256 + threadIdx.x;
  int n = idx >> 6, lane = idx & 63;
  // ---- per-node 8x8 head attention (lane -> channel lane*4..+3) ----
  int h = lane >> 3, g = lane & 7;
  const u16* base = QKV + n * 768;
  const bf16x8* qp = (const bf16x8*)(base + h * 32);
  const bf16x8* kp = (const bf16x8*)(base + 256 + g * 32);
  float s = 0.f;
#pragma unroll
  for (int t = 0; t < 4; t++) {
    bf16x8 qv = qp[t], kv = kp[t];
#pragma unroll
    for (int j = 0; j < 8; j++) s += b2f((u16)qv[j]) * b2f((u16)kv[j]);
  }
  s *= FK_SCALE;
  float mx = s;
#pragma unroll
  for (int off = 1; off < 8; off <<= 1) mx = fmaxf(mx, __shfl_xor(mx, off, 64));
  float p = __builtin_amdgcn_exp2f((s - mx) * LOG2E);
  float lsum = p;
#pragma unroll
  for (int off = 1; off < 8; off <<= 1) lsum += __shfl_xor(lsum, off, 64);
  float attn = p / lsum;
  float a4[4] = {0.f, 0.f, 0.f, 0.f};
#pragma unroll
  for (int g2 = 0; g2 < 8; g2++) {
    float a = __shfl(attn, (lane & 56) | g2, 64);
    bf16x4 vv = *(const bf16x4*)(base + 512 + g2 * 32 + g * 4);
#pragma unroll
    for (int j = 0; j < 4; j++) a4[j] += a * b2f((u16)vv[j]);
  }
  // ---- combine splits (shared fixed m) ----
  int c4 = lane * 4;
  float L = 0.f;
  f32x4 acc = {0.f, 0.f, 0.f, 0.f};
#pragma unroll
  for (int sp = 0; sp < NSPLIT; sp++) {
    L += Lv[sp * N_NODES + n];
    u16x4 ov = *(const u16x4*)(Op + (size_t)sp * N_NODES * 256 + (size_t)n * 256 + c4);
    acc.x += b2f(ov.x);
    acc.y += b2f(ov.y);
    acc.z += b2f(ov.z);
    acc.w += b2f(ov.w);
  }
  float invL = 1.0f / L;
  f32x4 res;
  res.x = fmaxf(acc.x * invL + a4[0], 0.f);
  res.y = fmaxf(acc.y * invL + a4[1], 0.f);
  res.z = fmaxf(acc.z * invL + a4[2], 0.f);
  res.w = fmaxf(acc.w * invL + a4[3], 0.f);
  *(f32x4*)(out + (size_t)n * 256 + c4) = res;
}

extern "C" void kernel_launch(void* const* d_in, const int* in_sizes, int n_in,
                              void* d_out, int out_size, void* d_ws, size_t ws_size,
                              hipStream_t stream) {
  const float* X = (const float*)d_in[0];
  const int* v_ids = (const int*)d_in[1];
  const int* e_ids = (const int*)d_in[2];
  const float* Wq = (const float*)d_in[3];
  const float* bq = (const float*)d_in[4];
  const float* Wk = (const float*)d_in[5];
  const float* bk = (const float*)d_in[6];
  const float* Wv = (const float*)d_in[7];
  const float* bv = (const float*)d_in[8];
  const float* Wke = (const float*)d_in[9];
  const float* bke = (const float*)d_in[10];
  float* out = (float*)d_out;

  char* ws = (char*)d_ws;
  u16* Xb = (u16*)(ws);                       // 8 MB   [N][256] bf16
  u16* QKV = (u16*)(ws + 8388608);            // 24 MB  [N][768] bf16
  u16* Wt = (u16*)(ws + 33554432);            // 512 KB
  float* bcat = (float*)(ws + 34078720);      // 4 KB
  int* hist = (int*)(ws + 34082816);          // 32 KB
  int* eoff = (int*)(ws + 34115584);          // 36 KB
  int* cur = (int*)(ws + 34152448);           // 32 KB
  int* perm = (int*)(ws + 34185216);          // 1 MB
  u16* Xe = (u16*)(ws + 35233792);            // 4 MB
  u16* XeT = (u16*)(ws + 39428096);           // 4 MB
  u16* Keb = (u16*)(ws + 43622400);           // 4 MB
  u16* Op = (u16*)(ws + 64593920);            // 24 MB  [3][N][256] bf16
  float* Lv = (float*)(ws + 98148352);        // 192 KB
  float* M2row = (float*)(ws + 98410496);     // 64 KB
  float* kappa = (float*)(ws + 98476032);     // 4 B

  hipMemsetAsync(hist, 0, 32768, stream);
  hipMemsetAsync(kappa, 0, 4, stream);
  k_cvt<<<4096, 256, 0, stream>>>(X, Xb);
  k_wt<<<dim3(4, 4, 4), 256, 0, stream>>>(Wq, Wk, Wv, Wke, Wt);
  k_bias<<<4, 256, 0, stream>>>(bq, bk, bv, bke, bcat);
  k_hist<<<256, 256, 0, stream>>>(e_ids, hist);
  k_scan<<<1, 256, 0, stream>>>(hist, eoff, cur);
  k_perm<<<256, 256, 0, stream>>>(v_ids, e_ids, cur, perm);
  k_gather<<<8192, 256, 0, stream>>>(Xb, perm, eoff, Xe);
  k_xt<<<dim3(128, 4), 256, 0, stream>>>(Xe, XeT);
  k_gemm64<<<dim3(256, 12), 256, 0, stream>>>(Xb, Wt, bcat, QKV, 768);
  k_gemm64<<<dim3(128, 4), 256, 0, stream>>>(Xe, Wt + 3 * 65536, bcat + 768, Keb, 256);
  k_knorm<<<256, 256, 0, stream>>>(Keb, kappa);
  k_qnorm<<<4096, 256, 0, stream>>>(QKV, kappa, M2row);
  hipFuncSetAttribute((const void*)k_flash, hipFuncAttributeMaxDynamicSharedMemorySize,
                      40960);
  k_flash<<<768, 256, 40960, stream>>>(QKV, Keb, XeT, M2row, Op, Lv);
  k_comb<<<4096, 256, 0, stream>>>(QKV, Op, Lv, out);
}

// Round 9
// 396.082 us; speedup vs baseline: 2.1792x; 2.1792x over previous
//
#include <hip/hip_runtime.h>

typedef unsigned short u16;
typedef unsigned int u32;
typedef __attribute__((ext_vector_type(4))) float f32x4;
typedef __attribute__((ext_vector_type(8))) short bf16x8;
typedef __attribute__((ext_vector_type(4))) short bf16x4;
typedef __attribute__((ext_vector_type(4))) u16 u16x4;

#define N_NODES 16384
#define N_EDGES 8192
#define FK_SCALE 0.17677669529663687f
#define LOG2E 1.4426950408889634f
#define C1EXP (FK_SCALE * LOG2E)
#define NSPLIT 2

typedef const u32 __attribute__((address_space(1))) gu32;
typedef u32 __attribute__((address_space(3))) lu32;

__device__ __forceinline__ void gl_lds16(const void* g, void* l) {
  __builtin_amdgcn_global_load_lds((gu32*)g, (lu32*)l, 16, 0, 0);
}

__device__ __forceinline__ float b2f(u16 u) {
  return __builtin_bit_cast(float, (u32)u << 16);
}
__device__ __forceinline__ u16 f2b(float f) {
  u32 u = __builtin_bit_cast(u32, f);
  u += 0x7fffu + ((u >> 16) & 1u);
  return (u16)(u >> 16);
}

// ---------------- X -> bf16 ----------------
__global__ __launch_bounds__(256) void k_cvt(const float* __restrict__ X,
                                             u16* __restrict__ Xb) {
  int i = blockIdx.x * 256 + threadIdx.x;
  f32x4 v = *(const f32x4*)(X + i * 4);
  u16x4 r;
  r.x = f2b(v.x); r.y = f2b(v.y); r.z = f2b(v.z); r.w = f2b(v.w);
  *(u16x4*)(Xb + i * 4) = r;
}

// ---------------- W transpose+cvt (coalesced via LDS) ----------------
__global__ __launch_bounds__(256) void k_wt(const float* __restrict__ Wq,
                                            const float* __restrict__ Wk,
                                            const float* __restrict__ Wv,
                                            const float* __restrict__ Wke,
                                            u16* __restrict__ Wt) {
  __shared__ float tile[64][65];
  int w = blockIdx.z;
  const float* W = (w == 0) ? Wq : (w == 1) ? Wk : (w == 2) ? Wv : Wke;
  int k0 = blockIdx.x * 64, n0 = blockIdx.y * 64;
  int tid = threadIdx.x;
#pragma unroll
  for (int i = 0; i < 16; i++) {
    int idx = i * 256 + tid;
    int kr = idx >> 6, nc = idx & 63;
    tile[nc][kr] = W[(k0 + kr) * 256 + n0 + nc];
  }
  __syncthreads();
#pragma unroll
  for (int i = 0; i < 16; i++) {
    int idx = i * 256 + tid;
    int nr = idx >> 6, kc = idx & 63;
    Wt[w * 65536 + (n0 + nr) * 256 + k0 + kc] = f2b(tile[nr][kc]);
  }
}

// ---------------- bias pack ----------------
__global__ __launch_bounds__(256) void k_bias(const float* __restrict__ bq,
                                              const float* __restrict__ bk,
                                              const float* __restrict__ bv,
                                              const float* __restrict__ bke,
                                              float* __restrict__ bcat) {
  int i = blockIdx.x * 256 + threadIdx.x;
  float v;
  if (i < 256) v = bq[i];
  else if (i < 512) v = bk[i - 256];
  else if (i < 768) v = bv[i - 512];
  else v = bke[i - 768];
  bcat[i] = v;
}

// ---------------- histogram of e_ids ----------------
__global__ __launch_bounds__(256) void k_hist(const int* __restrict__ e_ids,
                                              int* __restrict__ hist) {
  int base = blockIdx.x * 1024 + threadIdx.x;
#pragma unroll
  for (int k = 0; k < 4; k++) atomicAdd(&hist[e_ids[base + k * 256]], 1);
}

// ---------------- exclusive scan (1 block) ----------------
__global__ __launch_bounds__(256) void k_scan(const int* __restrict__ hist,
                                              int* __restrict__ eoff,
                                              int* __restrict__ cur) {
  __shared__ int ts[256];
  int t = threadIdx.x;
  int base = t * 32;
  int vals[32];
  int s = 0;
#pragma unroll
  for (int i = 0; i < 32; i++) { vals[i] = hist[base + i]; s += vals[i]; }
  ts[t] = s;
  __syncthreads();
  for (int off = 1; off < 256; off <<= 1) {
    int v = (t >= off) ? ts[t - off] : 0;
    __syncthreads();
    ts[t] += v;
    __syncthreads();
  }
  int ex = ts[t] - s;
#pragma unroll
  for (int i = 0; i < 32; i++) {
    eoff[base + i] = ex;
    cur[base + i] = ex;
    ex += vals[i];
  }
  if (t == 255) eoff[8192] = ex;
}

// ---------------- permute ----------------
__global__ __launch_bounds__(256) void k_perm(const int* __restrict__ v_ids,
                                              const int* __restrict__ e_ids,
                                              int* __restrict__ cur,
                                              int* __restrict__ perm) {
  int base = blockIdx.x * 1024 + threadIdx.x;
#pragma unroll
  for (int k = 0; k < 4; k++) {
    int i = base + k * 256;
    int e = e_ids[i];
    int v = v_ids[i];
    int pos = atomicAdd(&cur[e], 1);
    perm[pos] = v;
  }
}

// ---------------- per-edge gather-mean ----------------
__global__ __launch_bounds__(256) void k_gather(const u16* __restrict__ Xb,
                                                const int* __restrict__ perm,
                                                const int* __restrict__ eoff,
                                                u16* __restrict__ Xe) {
  __shared__ float red[4][256];
  int e = blockIdx.x;
  int tid = threadIdx.x, wave = tid >> 6, lane = tid & 63;
  int start = eoff[e], end = eoff[e + 1];
  f32x4 acc = {0.f, 0.f, 0.f, 0.f};
  for (int j = start + wave; j < end; j += 4) {
    int v = perm[j];
    bf16x4 x = *(const bf16x4*)(Xb + v * 256 + lane * 4);
#pragma unroll
    for (int c = 0; c < 4; c++) acc[c] += b2f((u16)x[c]);
  }
  *(f32x4*)&red[wave][lane * 4] = acc;
  __syncthreads();
  int t = tid;
  float s = red[0][t] + red[1][t] + red[2][t] + red[3][t];
  float m = s / fmaxf((float)(end - start), 1.0f);
  Xe[e * 256 + t] = f2b(m);
}

// ---------------- transpose Xe -> XeT ----------------
__global__ __launch_bounds__(256) void k_xt(const u16* __restrict__ Xe,
                                            u16* __restrict__ XeT) {
  __shared__ u16 tile[64][65];
  int e0 = blockIdx.x * 64, c0 = blockIdx.y * 64;
  int tid = threadIdx.x;
#pragma unroll
  for (int i = 0; i < 16; i++) {
    int idx = i * 256 + tid;
    int er = idx >> 6, cr = idx & 63;
    tile[cr][er] = Xe[(e0 + er) * 256 + c0 + cr];
  }
  __syncthreads();
#pragma unroll
  for (int i = 0; i < 16; i++) {
    int idx = i * 256 + tid;
    int cr = idx >> 6, er = idx & 63;
    XeT[(c0 + cr) * 8192 + e0 + er] = tile[cr][er];
  }
}

// ---------------- GEMM 64x64, K=256 ----------------
__global__ __launch_bounds__(256) void k_gemm64(const u16* __restrict__ A,
                                                const u16* __restrict__ Wt,
                                                const float* __restrict__ bias,
                                                u16* __restrict__ out,
                                                int ldout) {
  __shared__ u16 As[64 * 256];
  __shared__ u16 Bs[64 * 256];
  int tid = threadIdx.x;
  int mtile = blockIdx.x * 64;
  int gn = blockIdx.y * 64;
  const u16* Ap = A + mtile * 256;
  const u16* Bp = Wt + gn * 256;
#pragma unroll
  for (int i = 0; i < 8; i++) {
    gl_lds16(Ap + i * 2048 + tid * 8, As + i * 2048 + tid * 8);
    gl_lds16(Bp + i * 2048 + tid * 8, Bs + i * 2048 + tid * 8);
  }
  __syncthreads();
  int wave = tid >> 6, lane = tid & 63;
  int quad = lane >> 4, l16 = lane & 15;
  bf16x8 a[8];
#pragma unroll
  for (int kc = 0; kc < 8; kc++)
    a[kc] = *(const bf16x8*)(As + (wave * 16 + l16) * 256 + kc * 32 + quad * 8);
#pragma unroll
  for (int nt = 0; nt < 4; nt++) {
    f32x4 acc = {0.f, 0.f, 0.f, 0.f};
#pragma unroll
    for (int kc = 0; kc < 8; kc++) {
      bf16x8 b = *(const bf16x8*)(Bs + (nt * 16 + l16) * 256 + kc * 32 + quad * 8);
      acc = __builtin_amdgcn_mfma_f32_16x16x32_bf16(a[kc], b, acc, 0, 0, 0);
    }
#pragma unroll
    for (int r = 0; r < 4; r++) {
      int row = mtile + wave * 16 + quad * 4 + r;
      int col = gn + nt * 16 + l16;
      out[row * ldout + col] = f2b(acc[r] + bias[col]);
    }
  }
}

// ---------------- kappa = max_e ||Ke_e||^2 (256 atomics total) ----------------
__global__ __launch_bounds__(256) void k_knorm(const u16* __restrict__ Keb,
                                               float* __restrict__ kappa) {
  __shared__ float red[4];
  int tid = threadIdx.x;
  int wave = tid >> 6, lane = tid & 63;
  float mx = 0.f;
#pragma unroll
  for (int i = 0; i < 8; i++) {
    int e = blockIdx.x * 32 + wave * 8 + i;
    bf16x4 x = *(const bf16x4*)(Keb + e * 256 + lane * 4);
    float s = 0.f;
#pragma unroll
    for (int c = 0; c < 4; c++) { float v = b2f((u16)x[c]); s += v * v; }
#pragma unroll
    for (int off = 1; off < 64; off <<= 1) s += __shfl_xor(s, off, 64);
    mx = fmaxf(mx, s);
  }
  if (lane == 0) red[wave] = mx;
  __syncthreads();
  if (tid == 0) {
    float m = fmaxf(fmaxf(red[0], red[1]), fmaxf(red[2], red[3]));
    atomicMax((int*)kappa, __float_as_int(m));  // all values >= 0
  }
}

// ---------------- M2row[n] = ||Qe_n|| * sqrt(kappa) * scale * log2e ----------------
__global__ __launch_bounds__(256) void k_qnorm(const u16* __restrict__ QKV,
                                               const float* __restrict__ kappa,
                                               float* __restrict__ M2row) {
  int tid = threadIdx.x;
  int wave = tid >> 6, lane = tid & 63;
  int n = blockIdx.x * 4 + wave;
  bf16x4 x = *(const bf16x4*)(QKV + n * 768 + lane * 4);
  float s = 0.f;
#pragma unroll
  for (int c = 0; c < 4; c++) { float v = b2f((u16)x[c]); s += v * v; }
#pragma unroll
  for (int off = 1; off < 64; off <<= 1) s += __shfl_xor(s, off, 64);
  if (lane == 0) M2row[n] = sqrtf(s * kappa[0]) * C1EXP;
}

// ---------------- flash partial, fixed-m, Bq=16/wave, Bk=64 (R6 structure) ----------------
// 512 blocks = 256 q-tiles x 2 splits; 4 waves; 64 kt iters.
// LDS 72 KB: KeL [64][256] swz-8 (32K) | VL [256][64] swz-8 (32K) | PL [4][16][64] (8K).
// 2 blocks/CU; VGPR 112 measured (R6), no spills.
__global__ __launch_bounds__(256, 2) void k_flash(const u16* __restrict__ QKV,
                                                  const u16* __restrict__ Keb,
                                                  const u16* __restrict__ XeT,
                                                  const float* __restrict__ M2row,
                                                  u16* __restrict__ Op,
                                                  float* __restrict__ Lv) {
  extern __shared__ u16 sm[];
  u16* KeL = sm;               // [64][256] swizzled
  u16* VL = sm + 16384;        // [256][64] swizzled
  u16* PL = sm + 32768;        // [4][16][64] swizzled
  int tid = threadIdx.x;
  int wave = tid >> 6, lane = tid & 63;
  int quad = lane >> 4, l16 = lane & 15;
  int qt = blockIdx.x & 255;
  int split = blockIdx.x >> 8;
  int row0 = qt * 64 + wave * 16;
  u16* PLw = PL + (wave << 10);

  // Q fragments (1 m-tile / wave)
  bf16x8 qf[8];
#pragma unroll
  for (int kc = 0; kc < 8; kc++)
    qf[kc] = *(const bf16x8*)(QKV + (row0 + l16) * 768 + kc * 32 + quad * 8);

  float mb[4];
#pragma unroll
  for (int r = 0; r < 4; r++) mb[r] = M2row[row0 + quad * 4 + r];

  f32x4 o[16];
#pragma unroll
  for (int i = 0; i < 16; i++) o[i] = (f32x4){0.f, 0.f, 0.f, 0.f};
  float l[4] = {0.f, 0.f, 0.f, 0.f};

  for (int ktl = 0; ktl < 64; ktl++) {
    int ktg = split * 64 + ktl;
    __syncthreads();  // prev tile fully consumed
    {
      const u16* kp = Keb + ktg * 16384;
#pragma unroll
      for (int i = 0; i < 8; i++) {
        int s = i * 256 + tid;
        int r = s >> 5, p = s & 31;
        int c = (p & 24) | ((p & 7) ^ (r & 7));
        gl_lds16(kp + r * 256 + c * 8, KeL + s * 8);
      }
#pragma unroll
      for (int i = 0; i < 8; i++) {
        int s = i * 256 + tid;
        int c = s >> 3, p = s & 7;
        int k8 = p ^ (c & 7);
        gl_lds16(XeT + c * 8192 + ktg * 64 + k8 * 8, VL + s * 8);
      }
    }
    __syncthreads();  // tiles resident

    // QK^T per nt, immediate exp (fixed-m), P -> per-wave LDS
#pragma unroll
    for (int nt = 0; nt < 4; nt++) {
      f32x4 a = {0.f, 0.f, 0.f, 0.f};
#pragma unroll
      for (int kc = 0; kc < 8; kc++) {
        int r = nt * 16 + l16;
        int c = kc * 4 + quad;
        int p = (c & 24) | ((c & 7) ^ (r & 7));
        bf16x8 kb = *(const bf16x8*)(KeL + r * 256 + p * 8);
        a = __builtin_amdgcn_mfma_f32_16x16x32_bf16(qf[kc], kb, a, 0, 0, 0);
      }
      int col = nt * 16 + l16;
#pragma unroll
      for (int r = 0; r < 4; r++) {
        float pv = __builtin_amdgcn_exp2f(a[r] * C1EXP - mb[r]);
        l[r] += pv;
        int row = quad * 4 + r;
        PLw[row * 64 + (((col >> 3) ^ (row & 7)) << 3) + (col & 7)] = f2b(pv);
      }
    }
    // P A-fragments (same-wave LDS round trip, no barrier)
    bf16x8 pf[2];
#pragma unroll
    for (int kc2 = 0; kc2 < 2; kc2++) {
      int ck = kc2 * 4 + quad;
      pf[kc2] = *(const bf16x8*)(PLw + l16 * 64 + ((ck ^ (l16 & 7)) << 3));
    }
    // PV
#pragma unroll
    for (int ct = 0; ct < 16; ct++) {
#pragma unroll
      for (int kc2 = 0; kc2 < 2; kc2++) {
        int rv = ct * 16 + l16;
        int ck = kc2 * 4 + quad;
        bf16x8 vb = *(const bf16x8*)(VL + rv * 64 + ((ck ^ (rv & 7)) << 3));
        o[ct] = __builtin_amdgcn_mfma_f32_16x16x32_bf16(pf[kc2], vb, o[ct], 0, 0, 0);
      }
    }
  }

  // reduce row-sums across the 16 lanes of each row
#pragma unroll
  for (int off = 1; off < 16; off <<= 1)
#pragma unroll
    for (int r = 0; r < 4; r++) l[r] += __shfl_xor(l[r], off, 64);

  size_t obase = (size_t)split * N_NODES * 256;
#pragma unroll
  for (int ct = 0; ct < 16; ct++)
#pragma unroll
    for (int r = 0; r < 4; r++) {
      int row = row0 + quad * 4 + r;
      int col = ct * 16 + l16;
      Op[obase + (size_t)row * 256 + col] = f2b(o[ct][r]);
    }
  if (l16 == 0) {
#pragma unroll
    for (int r = 0; r < 4; r++)
      Lv[split * N_NODES + row0 + quad * 4 + r] = l[r];
  }
}

// ---------------- fused: node 8x8 head attention + split combine + ReLU ----------------
__global__ __launch_bounds__(256) void k_comb(const u16* __restrict__ QKV,
                                              const u16* __restrict__ Op,
                                              const float* __restrict__ Lv,
                                              float* __restrict__ out) {
  int idx = blockIdx.x * 256 + threadIdx.x;
  int n = idx >> 6, lane = idx & 63;
  // ---- per-node 8x8 head attention (lane -> channel lane*4..+3) ----
  int h = lane >> 3, g = lane & 7;
  const u16* base = QKV + n * 768;
  const bf16x8* qp = (const bf16x8*)(base + h * 32);
  const bf16x8* kp = (const bf16x8*)(base + 256 + g * 32);
  float s = 0.f;
#pragma unroll
  for (int t = 0; t < 4; t++) {
    bf16x8 qv = qp[t], kv = kp[t];
#pragma unroll
    for (int j = 0; j < 8; j++) s += b2f((u16)qv[j]) * b2f((u16)kv[j]);
  }
  s *= FK_SCALE;
  float mx = s;
#pragma unroll
  for (int off = 1; off < 8; off <<= 1) mx = fmaxf(mx, __shfl_xor(mx, off, 64));
  float p = __builtin_amdgcn_exp2f((s - mx) * LOG2E);
  float lsum = p;
#pragma unroll
  for (int off = 1; off < 8; off <<= 1) lsum += __shfl_xor(lsum, off, 64);
  float attn = p / lsum;
  float a4[4] = {0.f, 0.f, 0.f, 0.f};
#pragma unroll
  for (int g2 = 0; g2 < 8; g2++) {
    float a = __shfl(attn, (lane & 56) | g2, 64);
    bf16x4 vv = *(const bf16x4*)(base + 512 + g2 * 32 + g * 4);
#pragma unroll
    for (int j = 0; j < 4; j++) a4[j] += a * b2f((u16)vv[j]);
  }
  // ---- combine splits (shared fixed m) ----
  int c4 = lane * 4;
  float L = 0.f;
  f32x4 acc = {0.f, 0.f, 0.f, 0.f};
#pragma unroll
  for (int sp = 0; sp < NSPLIT; sp++) {
    L += Lv[sp * N_NODES + n];
    u16x4 ov = *(const u16x4*)(Op + (size_t)sp * N_NODES * 256 + (size_t)n * 256 + c4);
    acc.x += b2f(ov.x);
    acc.y += b2f(ov.y);
    acc.z += b2f(ov.z);
    acc.w += b2f(ov.w);
  }
  float invL = 1.0f / L;
  f32x4 res;
  res.x = fmaxf(acc.x * invL + a4[0], 0.f);
  res.y = fmaxf(acc.y * invL + a4[1], 0.f);
  res.z = fmaxf(acc.z * invL + a4[2], 0.f);
  res.w = fmaxf(acc.w * invL + a4[3], 0.f);
  *(f32x4*)(out + (size_t)n * 256 + c4) = res;
}

extern "C" void kernel_launch(void* const* d_in, const int* in_sizes, int n_in,
                              void* d_out, int out_size, void* d_ws, size_t ws_size,
                              hipStream_t stream) {
  const float* X = (const float*)d_in[0];
  const int* v_ids = (const int*)d_in[1];
  const int* e_ids = (const int*)d_in[2];
  const float* Wq = (const float*)d_in[3];
  const float* bq = (const float*)d_in[4];
  const float* Wk = (const float*)d_in[5];
  const float* bk = (const float*)d_in[6];
  const float* Wv = (const float*)d_in[7];
  const float* bv = (const float*)d_in[8];
  const float* Wke = (const float*)d_in[9];
  const float* bke = (const float*)d_in[10];
  float* out = (float*)d_out;

  char* ws = (char*)d_ws;
  u16* Xb = (u16*)(ws);                       // 8 MB   [N][256] bf16
  u16* QKV = (u16*)(ws + 8388608);            // 24 MB  [N][768] bf16
  u16* Wt = (u16*)(ws + 33554432);            // 512 KB
  float* bcat = (float*)(ws + 34078720);      // 4 KB
  int* hist = (int*)(ws + 34082816);          // 32 KB
  int* eoff = (int*)(ws + 34115584);          // 36 KB
  int* cur = (int*)(ws + 34152448);           // 32 KB
  int* perm = (int*)(ws + 34185216);          // 1 MB
  u16* Xe = (u16*)(ws + 35233792);            // 4 MB
  u16* XeT = (u16*)(ws + 39428096);           // 4 MB
  u16* Keb = (u16*)(ws + 43622400);           // 4 MB
  u16* Op = (u16*)(ws + 64593920);            // 16 MB  [2][N][256] bf16
  float* Lv = (float*)(ws + 98148352);        // 128 KB
  float* M2row = (float*)(ws + 98410496);     // 64 KB
  float* kappa = (float*)(ws + 98476032);     // 4 B

  hipMemsetAsync(hist, 0, 32768, stream);
  hipMemsetAsync(kappa, 0, 4, stream);
  k_cvt<<<4096, 256, 0, stream>>>(X, Xb);
  k_wt<<<dim3(4, 4, 4), 256, 0, stream>>>(Wq, Wk, Wv, Wke, Wt);
  k_bias<<<4, 256, 0, stream>>>(bq, bk, bv, bke, bcat);
  k_hist<<<256, 256, 0, stream>>>(e_ids, hist);
  k_scan<<<1, 256, 0, stream>>>(hist, eoff, cur);
  k_perm<<<256, 256, 0, stream>>>(v_ids, e_ids, cur, perm);
  k_gather<<<8192, 256, 0, stream>>>(Xb, perm, eoff, Xe);
  k_xt<<<dim3(128, 4), 256, 0, stream>>>(Xe, XeT);
  k_gemm64<<<dim3(256, 12), 256, 0, stream>>>(Xb, Wt, bcat, QKV, 768);
  k_gemm64<<<dim3(128, 4), 256, 0, stream>>>(Xe, Wt + 3 * 65536, bcat + 768, Keb, 256);
  k_knorm<<<256, 256, 0, stream>>>(Keb, kappa);
  k_qnorm<<<4096, 256, 0, stream>>>(QKV, kappa, M2row);
  hipFuncSetAttribute((const void*)k_flash, hipFuncAttributeMaxDynamicSharedMemorySize,
                      73728);
  k_flash<<<512, 256, 73728, stream>>>(QKV, Keb, XeT, M2row, Op, Lv);
  k_comb<<<4096, 256, 0, stream>>>(QKV, Op, Lv, out);
}

// Round 10
// 376.271 us; speedup vs baseline: 2.2939x; 1.0526x over previous
//
#include <hip/hip_runtime.h>

typedef unsigned short u16;
typedef unsigned int u32;
typedef __attribute__((ext_vector_type(4))) float f32x4;
typedef __attribute__((ext_vector_type(16))) float f32x16;
typedef __attribute__((ext_vector_type(8))) short bf16x8;
typedef __attribute__((ext_vector_type(4))) short bf16x4;
typedef __attribute__((ext_vector_type(4))) u16 u16x4;

#define N_NODES 16384
#define N_EDGES 8192
#define FK_SCALE 0.17677669529663687f
#define LOG2E 1.4426950408889634f
#define C1EXP (FK_SCALE * LOG2E)
#define NSPLIT 2

typedef const u32 __attribute__((address_space(1))) gu32;
typedef u32 __attribute__((address_space(3))) lu32;

__device__ __forceinline__ void gl_lds16(const void* g, void* l) {
  __builtin_amdgcn_global_load_lds((gu32*)g, (lu32*)l, 16, 0, 0);
}

__device__ __forceinline__ float b2f(u16 u) {
  return __builtin_bit_cast(float, (u32)u << 16);
}
__device__ __forceinline__ u16 f2b(float f) {
  u32 u = __builtin_bit_cast(u32, f);
  u += 0x7fffu + ((u >> 16) & 1u);
  return (u16)(u >> 16);
}

// ---------------- X -> bf16 ----------------
__global__ __launch_bounds__(256) void k_cvt(const float* __restrict__ X,
                                             u16* __restrict__ Xb) {
  int i = blockIdx.x * 256 + threadIdx.x;
  f32x4 v = *(const f32x4*)(X + i * 4);
  u16x4 r;
  r.x = f2b(v.x); r.y = f2b(v.y); r.z = f2b(v.z); r.w = f2b(v.w);
  *(u16x4*)(Xb + i * 4) = r;
}

// ---------------- W transpose+cvt (coalesced via LDS) ----------------
__global__ __launch_bounds__(256) void k_wt(const float* __restrict__ Wq,
                                            const float* __restrict__ Wk,
                                            const float* __restrict__ Wv,
                                            const float* __restrict__ Wke,
                                            u16* __restrict__ Wt) {
  __shared__ float tile[64][65];
  int w = blockIdx.z;
  const float* W = (w == 0) ? Wq : (w == 1) ? Wk : (w == 2) ? Wv : Wke;
  int k0 = blockIdx.x * 64, n0 = blockIdx.y * 64;
  int tid = threadIdx.x;
#pragma unroll
  for (int i = 0; i < 16; i++) {
    int idx = i * 256 + tid;
    int kr = idx >> 6, nc = idx & 63;
    tile[nc][kr] = W[(k0 + kr) * 256 + n0 + nc];
  }
  __syncthreads();
#pragma unroll
  for (int i = 0; i < 16; i++) {
    int idx = i * 256 + tid;
    int nr = idx >> 6, kc = idx & 63;
    Wt[w * 65536 + (n0 + nr) * 256 + k0 + kc] = f2b(tile[nr][kc]);
  }
}

// ---------------- bias pack ----------------
__global__ __launch_bounds__(256) void k_bias(const float* __restrict__ bq,
                                              const float* __restrict__ bk,
                                              const float* __restrict__ bv,
                                              const float* __restrict__ bke,
                                              float* __restrict__ bcat) {
  int i = blockIdx.x * 256 + threadIdx.x;
  float v;
  if (i < 256) v = bq[i];
  else if (i < 512) v = bk[i - 256];
  else if (i < 768) v = bv[i - 512];
  else v = bke[i - 768];
  bcat[i] = v;
}

// ---------------- histogram of e_ids ----------------
__global__ __launch_bounds__(256) void k_hist(const int* __restrict__ e_ids,
                                              int* __restrict__ hist) {
  int base = blockIdx.x * 1024 + threadIdx.x;
#pragma unroll
  for (int k = 0; k < 4; k++) atomicAdd(&hist[e_ids[base + k * 256]], 1);
}

// ---------------- exclusive scan (1 block) ----------------
__global__ __launch_bounds__(256) void k_scan(const int* __restrict__ hist,
                                              int* __restrict__ eoff,
                                              int* __restrict__ cur) {
  __shared__ int ts[256];
  int t = threadIdx.x;
  int base = t * 32;
  int vals[32];
  int s = 0;
#pragma unroll
  for (int i = 0; i < 32; i++) { vals[i] = hist[base + i]; s += vals[i]; }
  ts[t] = s;
  __syncthreads();
  for (int off = 1; off < 256; off <<= 1) {
    int v = (t >= off) ? ts[t - off] : 0;
    __syncthreads();
    ts[t] += v;
    __syncthreads();
  }
  int ex = ts[t] - s;
#pragma unroll
  for (int i = 0; i < 32; i++) {
    eoff[base + i] = ex;
    cur[base + i] = ex;
    ex += vals[i];
  }
  if (t == 255) eoff[8192] = ex;
}

// ---------------- permute ----------------
__global__ __launch_bounds__(256) void k_perm(const int* __restrict__ v_ids,
                                              const int* __restrict__ e_ids,
                                              int* __restrict__ cur,
                                              int* __restrict__ perm) {
  int base = blockIdx.x * 1024 + threadIdx.x;
#pragma unroll
  for (int k = 0; k < 4; k++) {
    int i = base + k * 256;
    int e = e_ids[i];
    int v = v_ids[i];
    int pos = atomicAdd(&cur[e], 1);
    perm[pos] = v;
  }
}

// ---------------- per-edge gather-mean ----------------
__global__ __launch_bounds__(256) void k_gather(const u16* __restrict__ Xb,
                                                const int* __restrict__ perm,
                                                const int* __restrict__ eoff,
                                                u16* __restrict__ Xe) {
  __shared__ float red[4][256];
  int e = blockIdx.x;
  int tid = threadIdx.x, wave = tid >> 6, lane = tid & 63;
  int start = eoff[e], end = eoff[e + 1];
  f32x4 acc = {0.f, 0.f, 0.f, 0.f};
  for (int j = start + wave; j < end; j += 4) {
    int v = perm[j];
    bf16x4 x = *(const bf16x4*)(Xb + v * 256 + lane * 4);
#pragma unroll
    for (int c = 0; c < 4; c++) acc[c] += b2f((u16)x[c]);
  }
  *(f32x4*)&red[wave][lane * 4] = acc;
  __syncthreads();
  int t = tid;
  float s = red[0][t] + red[1][t] + red[2][t] + red[3][t];
  float m = s / fmaxf((float)(end - start), 1.0f);
  Xe[e * 256 + t] = f2b(m);
}

// ---------------- transpose Xe -> XeTc[key>>3][ch][key&7] (chunk-major) ----------------
__global__ __launch_bounds__(256) void k_xt(const u16* __restrict__ Xe,
                                            u16* __restrict__ XeTc) {
  __shared__ u16 tile[64][65];
  int e0 = blockIdx.x * 64, c0 = blockIdx.y * 64;
  int tid = threadIdx.x;
#pragma unroll
  for (int i = 0; i < 16; i++) {
    int idx = i * 256 + tid;
    int er = idx >> 6, cr = idx & 63;
    tile[cr][er] = Xe[(e0 + er) * 256 + c0 + cr];
  }
  __syncthreads();
#pragma unroll
  for (int i = 0; i < 16; i++) {
    int idx = i * 256 + tid;
    int cr = idx >> 6, er = idx & 63;
    int e = e0 + er;
    XeTc[(size_t)(e >> 3) * 2048 + (c0 + cr) * 8 + (e & 7)] = tile[cr][er];
  }
}

// ---------------- GEMM 64x64, K=256, row-major out ----------------
__global__ __launch_bounds__(256) void k_gemm64(const u16* __restrict__ A,
                                                const u16* __restrict__ Wt,
                                                const float* __restrict__ bias,
                                                u16* __restrict__ out,
                                                int ldout) {
  __shared__ u16 As[64 * 256];
  __shared__ u16 Bs[64 * 256];
  int tid = threadIdx.x;
  int mtile = blockIdx.x * 64;
  int gn = blockIdx.y * 64;
  const u16* Ap = A + mtile * 256;
  const u16* Bp = Wt + gn * 256;
#pragma unroll
  for (int i = 0; i < 8; i++) {
    gl_lds16(Ap + i * 2048 + tid * 8, As + i * 2048 + tid * 8);
    gl_lds16(Bp + i * 2048 + tid * 8, Bs + i * 2048 + tid * 8);
  }
  __syncthreads();
  int wave = tid >> 6, lane = tid & 63;
  int quad = lane >> 4, l16 = lane & 15;
  bf16x8 a[8];
#pragma unroll
  for (int kc = 0; kc < 8; kc++)
    a[kc] = *(const bf16x8*)(As + (wave * 16 + l16) * 256 + kc * 32 + quad * 8);
#pragma unroll
  for (int nt = 0; nt < 4; nt++) {
    f32x4 acc = {0.f, 0.f, 0.f, 0.f};
#pragma unroll
    for (int kc = 0; kc < 8; kc++) {
      bf16x8 b = *(const bf16x8*)(Bs + (nt * 16 + l16) * 256 + kc * 32 + quad * 8);
      acc = __builtin_amdgcn_mfma_f32_16x16x32_bf16(a[kc], b, acc, 0, 0, 0);
    }
#pragma unroll
    for (int r = 0; r < 4; r++) {
      int row = mtile + wave * 16 + quad * 4 + r;
      int col = gn + nt * 16 + l16;
      out[row * ldout + col] = f2b(acc[r] + bias[col]);
    }
  }
}

// ---------------- GEMM 64x64 for Ke, writes chunk-major KebT[c][key][8] ----------------
__global__ __launch_bounds__(256) void k_gemmke(const u16* __restrict__ A,
                                                const u16* __restrict__ Wt,
                                                const float* __restrict__ bias,
                                                u16* __restrict__ KebT) {
  __shared__ u16 As[64 * 256];
  __shared__ u16 Bs[64 * 256];
  int tid = threadIdx.x;
  int mtile = blockIdx.x * 64;
  int gn = blockIdx.y * 64;
  const u16* Ap = A + mtile * 256;
  const u16* Bp = Wt + gn * 256;
#pragma unroll
  for (int i = 0; i < 8; i++) {
    gl_lds16(Ap + i * 2048 + tid * 8, As + i * 2048 + tid * 8);
    gl_lds16(Bp + i * 2048 + tid * 8, Bs + i * 2048 + tid * 8);
  }
  __syncthreads();
  int wave = tid >> 6, lane = tid & 63;
  int quad = lane >> 4, l16 = lane & 15;
  bf16x8 a[8];
#pragma unroll
  for (int kc = 0; kc < 8; kc++)
    a[kc] = *(const bf16x8*)(As + (wave * 16 + l16) * 256 + kc * 32 + quad * 8);
#pragma unroll
  for (int nt = 0; nt < 4; nt++) {
    f32x4 acc = {0.f, 0.f, 0.f, 0.f};
#pragma unroll
    for (int kc = 0; kc < 8; kc++) {
      bf16x8 b = *(const bf16x8*)(Bs + (nt * 16 + l16) * 256 + kc * 32 + quad * 8);
      acc = __builtin_amdgcn_mfma_f32_16x16x32_bf16(a[kc], b, acc, 0, 0, 0);
    }
#pragma unroll
    for (int r = 0; r < 4; r++) {
      int row = mtile + wave * 16 + quad * 4 + r;  // key
      int col = gn + nt * 16 + l16;                // k-channel
      KebT[(size_t)(col >> 3) * 65536 + row * 8 + (col & 7)] = f2b(acc[r] + bias[col]);
    }
  }
}

// ---------------- flash partial, 32x32x16 MFMA, wave-pair design ----------------
// 512 blocks = 256 q-tiles x 2 splits; 4 waves = 2 pairs x 32 rows; Bk=64; 64 iters.
// Pair (w_kh0, w_kh1): QK split by key-halves, PV split by col-halves; P via LDS.
// LDS 74 KB: KeL [32c][64key][8] 32K | VLT [8kc][256ch][8] 32K | PL [2][32][64] 8K | lsum.
// All hot LDS reads lane-contiguous (chunk-major) -> conflict-free. No fixed-m
// (scores bounded: |s*c1| < ~10 << 127, exp2 cannot overflow).
__global__ __launch_bounds__(256, 2) void k_flash(const u16* __restrict__ QKV,
                                                  const u16* __restrict__ KebT,
                                                  const u16* __restrict__ XeTc,
                                                  u16* __restrict__ Op,
                                                  float* __restrict__ Lv) {
  extern __shared__ u16 sm[];
  u16* KeL = sm;               // [32 c][64 key][8 u16]
  u16* VLT = sm + 16384;       // [8 kc][256 ch][8 u16]
  u16* PL = sm + 32768;        // [2 pair][32 row][64 key] u16, XOR-8 swizzle
  float* lsum = (float*)(sm + 36864);  // [64]
  int tid = threadIdx.x;
  int wave = tid >> 6, lane = tid & 63;
  int l31 = lane & 31, half = lane >> 5;
  int pair = wave >> 1, kh = wave & 1;
  int qt = blockIdx.x & 255;
  int split = blockIdx.x >> 8;
  int rowp0 = qt * 64 + pair * 32;
  u16* PLp = PL + pair * 2048;

  if (tid < 64) lsum[tid] = 0.f;

  // Q A-fragments: A[m=l31][k=half*8+j] per 16 k-steps
  bf16x8 qf[16];
#pragma unroll
  for (int ks = 0; ks < 16; ks++)
    qf[ks] = *(const bf16x8*)(QKV + (rowp0 + l31) * 768 + ks * 16 + half * 8);

  f32x16 o[4];
#pragma unroll
  for (int i = 0; i < 4; i++)
#pragma unroll
    for (int r = 0; r < 16; r++) o[i][r] = 0.f;
  float l[16];
#pragma unroll
  for (int r = 0; r < 16; r++) l[r] = 0.f;

  for (int ktl = 0; ktl < 64; ktl++) {
    int ktg = split * 64 + ktl;
    int kbase = ktg * 64;
    __syncthreads();  // prev tile fully consumed
    // stage KeL (chunk-major, coalesced)
#pragma unroll
    for (int i = 0; i < 8; i++) {
      int s = i * 256 + tid;
      int c = s >> 6, r = s & 63;
      gl_lds16(KebT + ((size_t)c * 8192 + kbase + r) * 8, KeL + s * 8);
    }
    // stage VLT (chunk-major, coalesced)
    int kb8 = ktg * 8;
#pragma unroll
    for (int i = 0; i < 8; i++) {
      int s = i * 256 + tid;
      int kc = s >> 8, ch = s & 255;
      gl_lds16(XeTc + ((size_t)(kb8 + kc) * 256 + ch) * 8, VLT + s * 8);
    }
    __syncthreads();  // tiles resident

    // QK^T: 32 rows x 32 keys (this wave's key-half), 16 chained 32x32x16
    f32x16 sc;
#pragma unroll
    for (int r = 0; r < 16; r++) sc[r] = 0.f;
#pragma unroll
    for (int ks = 0; ks < 16; ks++) {
      int c = ks * 2 + half;
      bf16x8 kb = *(const bf16x8*)(KeL + c * 512 + (kh * 32 + l31) * 8);
      sc = __builtin_amdgcn_mfma_f32_32x32x16_bf16(qf[ks], kb, sc, 0, 0, 0);
    }
    // exp (no shift) + P -> LDS (C/D layout: col=l31, row=(reg&3)+8*(reg>>2)+4*half)
#pragma unroll
    for (int reg = 0; reg < 16; reg++) {
      float pv = __builtin_amdgcn_exp2f(sc[reg] * C1EXP);
      l[reg] += pv;
      int row = (reg & 3) + 8 * (reg >> 2) + 4 * half;
      int col = kh * 32 + l31;
      PLp[row * 64 + (((col >> 3) ^ (row & 7)) << 3) + (col & 7)] = f2b(pv);
    }
    __syncthreads();  // P visible across the pair
    // P A-fragments: A[m=l31][k=ks*16+half*8+j]
    bf16x8 pf[4];
#pragma unroll
    for (int ks = 0; ks < 4; ks++) {
      int pc = ks * 2 + half;
      pf[ks] = *(const bf16x8*)(PLp + l31 * 64 + ((pc ^ (l31 & 7)) << 3));
    }
    // PV: rows 0-31 x this wave's col-half (4 ct of 32)
#pragma unroll
    for (int ct = 0; ct < 4; ct++) {
#pragma unroll
      for (int ks = 0; ks < 4; ks++) {
        int kc = ks * 2 + half;
        int ch = kh * 128 + ct * 32 + l31;
        bf16x8 vb = *(const bf16x8*)(VLT + kc * 2048 + ch * 8);
        o[ct] = __builtin_amdgcn_mfma_f32_32x32x16_bf16(pf[ks], vb, o[ct], 0, 0, 0);
      }
    }
  }

  // l: reduce across the 32 key-lanes of this wave's half
#pragma unroll
  for (int off = 1; off < 32; off <<= 1)
#pragma unroll
    for (int r = 0; r < 16; r++) l[r] += __shfl_xor(l[r], off, 64);
  if (l31 == 0) {
#pragma unroll
    for (int reg = 0; reg < 16; reg++) {
      int row = (reg & 3) + 8 * (reg >> 2) + 4 * half;
      atomicAdd(&lsum[pair * 32 + row], l[reg]);
    }
  }
  __syncthreads();

  size_t obase = (size_t)split * N_NODES * 256;
#pragma unroll
  for (int ct = 0; ct < 4; ct++)
#pragma unroll
    for (int reg = 0; reg < 16; reg++) {
      int row = rowp0 + (reg & 3) + 8 * (reg >> 2) + 4 * half;
      int col = kh * 128 + ct * 32 + l31;
      Op[obase + (size_t)row * 256 + col] = f2b(o[ct][reg]);
    }
  if (tid < 64) Lv[split * N_NODES + qt * 64 + tid] = lsum[tid];
}

// ---------------- fused: node 8x8 head attention + split combine + ReLU ----------------
__global__ __launch_bounds__(256) void k_comb(const u16* __restrict__ QKV,
                                              const u16* __restrict__ Op,
                                              const float* __restrict__ Lv,
                                              float* __restrict__ out) {
  int idx = blockIdx.x * 256 + threadIdx.x;
  int n = idx >> 6, lane = idx & 63;
  int h = lane >> 3, g = lane & 7;
  const u16* base = QKV + n * 768;
  const bf16x8* qp = (const bf16x8*)(base + h * 32);
  const bf16x8* kp = (const bf16x8*)(base + 256 + g * 32);
  float s = 0.f;
#pragma unroll
  for (int t = 0; t < 4; t++) {
    bf16x8 qv = qp[t], kv = kp[t];
#pragma unroll
    for (int j = 0; j < 8; j++) s += b2f((u16)qv[j]) * b2f((u16)kv[j]);
  }
  s *= FK_SCALE;
  float mx = s;
#pragma unroll
  for (int off = 1; off < 8; off <<= 1) mx = fmaxf(mx, __shfl_xor(mx, off, 64));
  float p = __builtin_amdgcn_exp2f((s - mx) * LOG2E);
  float lsum = p;
#pragma unroll
  for (int off = 1; off < 8; off <<= 1) lsum += __shfl_xor(lsum, off, 64);
  float attn = p / lsum;
  float a4[4] = {0.f, 0.f, 0.f, 0.f};
#pragma unroll
  for (int g2 = 0; g2 < 8; g2++) {
    float a = __shfl(attn, (lane & 56) | g2, 64);
    bf16x4 vv = *(const bf16x4*)(base + 512 + g2 * 32 + g * 4);
#pragma unroll
    for (int j = 0; j < 4; j++) a4[j] += a * b2f((u16)vv[j]);
  }
  int c4 = lane * 4;
  float L = 0.f;
  f32x4 acc = {0.f, 0.f, 0.f, 0.f};
#pragma unroll
  for (int sp = 0; sp < NSPLIT; sp++) {
    L += Lv[sp * N_NODES + n];
    u16x4 ov = *(const u16x4*)(Op + (size_t)sp * N_NODES * 256 + (size_t)n * 256 + c4);
    acc.x += b2f(ov.x);
    acc.y += b2f(ov.y);
    acc.z += b2f(ov.z);
    acc.w += b2f(ov.w);
  }
  float invL = 1.0f / L;
  f32x4 res;
  res.x = fmaxf(acc.x * invL + a4[0], 0.f);
  res.y = fmaxf(acc.y * invL + a4[1], 0.f);
  res.z = fmaxf(acc.z * invL + a4[2], 0.f);
  res.w = fmaxf(acc.w * invL + a4[3], 0.f);
  *(f32x4*)(out + (size_t)n * 256 + c4) = res;
}

extern "C" void kernel_launch(void* const* d_in, const int* in_sizes, int n_in,
                              void* d_out, int out_size, void* d_ws, size_t ws_size,
                              hipStream_t stream) {
  const float* X = (const float*)d_in[0];
  const int* v_ids = (const int*)d_in[1];
  const int* e_ids = (const int*)d_in[2];
  const float* Wq = (const float*)d_in[3];
  const float* bq = (const float*)d_in[4];
  const float* Wk = (const float*)d_in[5];
  const float* bk = (const float*)d_in[6];
  const float* Wv = (const float*)d_in[7];
  const float* bv = (const float*)d_in[8];
  const float* Wke = (const float*)d_in[9];
  const float* bke = (const float*)d_in[10];
  float* out = (float*)d_out;

  char* ws = (char*)d_ws;
  u16* Xb = (u16*)(ws);                       // 8 MB   [N][256] bf16
  u16* QKV = (u16*)(ws + 8388608);            // 24 MB  [N][768] bf16
  u16* Wt = (u16*)(ws + 33554432);            // 512 KB
  float* bcat = (float*)(ws + 34078720);      // 4 KB
  int* hist = (int*)(ws + 34082816);          // 32 KB
  int* eoff = (int*)(ws + 34115584);          // 36 KB
  int* cur = (int*)(ws + 34152448);           // 32 KB
  int* perm = (int*)(ws + 34185216);          // 1 MB
  u16* Xe = (u16*)(ws + 35233792);            // 4 MB   [E][256]
  u16* XeTc = (u16*)(ws + 39428096);          // 4 MB   [E/8][256][8]
  u16* KebT = (u16*)(ws + 43622400);          // 4 MB   [32][E][8]
  u16* Op = (u16*)(ws + 64593920);            // 16 MB  [2][N][256] bf16
  float* Lv = (float*)(ws + 98148352);        // 128 KB

  hipMemsetAsync(hist, 0, 32768, stream);
  k_cvt<<<4096, 256, 0, stream>>>(X, Xb);
  k_wt<<<dim3(4, 4, 4), 256, 0, stream>>>(Wq, Wk, Wv, Wke, Wt);
  k_bias<<<4, 256, 0, stream>>>(bq, bk, bv, bke, bcat);
  k_hist<<<256, 256, 0, stream>>>(e_ids, hist);
  k_scan<<<1, 256, 0, stream>>>(hist, eoff, cur);
  k_perm<<<256, 256, 0, stream>>>(v_ids, e_ids, cur, perm);
  k_gather<<<8192, 256, 0, stream>>>(Xb, perm, eoff, Xe);
  k_xt<<<dim3(128, 4), 256, 0, stream>>>(Xe, XeTc);
  k_gemm64<<<dim3(256, 12), 256, 0, stream>>>(Xb, Wt, bcat, QKV, 768);
  k_gemmke<<<dim3(128, 4), 256, 0, stream>>>(Xe, Wt + 3 * 65536, bcat + 768, KebT);
  hipFuncSetAttribute((const void*)k_flash, hipFuncAttributeMaxDynamicSharedMemorySize,
                      73984);
  k_flash<<<512, 256, 73984, stream>>>(QKV, KebT, XeTc, Op, Lv);
  k_comb<<<4096, 256, 0, stream>>>(QKV, Op, Lv, out);
}

// Round 11
// 366.805 us; speedup vs baseline: 2.3531x; 1.0258x over previous
//
#include <hip/hip_runtime.h>

typedef unsigned short u16;
typedef unsigned int u32;
typedef __attribute__((ext_vector_type(4))) float f32x4;
typedef __attribute__((ext_vector_type(16))) float f32x16;
typedef __attribute__((ext_vector_type(8))) short bf16x8;
typedef __attribute__((ext_vector_type(4))) short bf16x4;
typedef __attribute__((ext_vector_type(4))) u16 u16x4;

#define N_NODES 16384
#define N_EDGES 8192
#define FK_SCALE 0.17677669529663687f
#define LOG2E 1.4426950408889634f
#define C1EXP (FK_SCALE * LOG2E)

typedef const u32 __attribute__((address_space(1))) gu32;
typedef u32 __attribute__((address_space(3))) lu32;

__device__ __forceinline__ void gl_lds16(const void* g, void* l) {
  __builtin_amdgcn_global_load_lds((gu32*)g, (lu32*)l, 16, 0, 0);
}

__device__ __forceinline__ float b2f(u16 u) {
  return __builtin_bit_cast(float, (u32)u << 16);
}
__device__ __forceinline__ u16 f2b(float f) {
  u32 u = __builtin_bit_cast(u32, f);
  u += 0x7fffu + ((u >> 16) & 1u);
  return (u16)(u >> 16);
}

// ---------------- fused: X -> bf16 + e_ids histogram ----------------
__global__ __launch_bounds__(256) void k_prep(const float* __restrict__ X,
                                              const int* __restrict__ e_ids,
                                              u16* __restrict__ Xb,
                                              int* __restrict__ hist) {
  int i = blockIdx.x * 256 + threadIdx.x;
  f32x4 v = *(const f32x4*)(X + i * 4);
  u16x4 r;
  r.x = f2b(v.x); r.y = f2b(v.y); r.z = f2b(v.z); r.w = f2b(v.w);
  *(u16x4*)(Xb + i * 4) = r;
  if (threadIdx.x < 64) atomicAdd(&hist[e_ids[blockIdx.x * 64 + threadIdx.x]], 1);
}

// ---------------- W transpose+cvt (coalesced via LDS) + bias pack ----------------
__global__ __launch_bounds__(256) void k_wt(const float* __restrict__ Wq,
                                            const float* __restrict__ Wk,
                                            const float* __restrict__ Wv,
                                            const float* __restrict__ Wke,
                                            const float* __restrict__ bq,
                                            const float* __restrict__ bk,
                                            const float* __restrict__ bv,
                                            const float* __restrict__ bke,
                                            u16* __restrict__ Wt,
                                            float* __restrict__ bcat) {
  __shared__ float tile[64][65];
  int w = blockIdx.z;
  const float* W = (w == 0) ? Wq : (w == 1) ? Wk : (w == 2) ? Wv : Wke;
  int k0 = blockIdx.x * 64, n0 = blockIdx.y * 64;
  int tid = threadIdx.x;
  if (blockIdx.x == 0 && blockIdx.y == 0) {
    const float* b = (w == 0) ? bq : (w == 1) ? bk : (w == 2) ? bv : bke;
    bcat[w * 256 + tid] = b[tid];
  }
#pragma unroll
  for (int i = 0; i < 16; i++) {
    int idx = i * 256 + tid;
    int kr = idx >> 6, nc = idx & 63;
    tile[nc][kr] = W[(k0 + kr) * 256 + n0 + nc];
  }
  __syncthreads();
#pragma unroll
  for (int i = 0; i < 16; i++) {
    int idx = i * 256 + tid;
    int nr = idx >> 6, kc = idx & 63;
    Wt[w * 65536 + (n0 + nr) * 256 + k0 + kc] = f2b(tile[nr][kc]);
  }
}

// ---------------- exclusive scan (1 block) ----------------
__global__ __launch_bounds__(256) void k_scan(const int* __restrict__ hist,
                                              int* __restrict__ eoff,
                                              int* __restrict__ cur) {
  __shared__ int ts[256];
  int t = threadIdx.x;
  int base = t * 32;
  int vals[32];
  int s = 0;
#pragma unroll
  for (int i = 0; i < 32; i++) { vals[i] = hist[base + i]; s += vals[i]; }
  ts[t] = s;
  __syncthreads();
  for (int off = 1; off < 256; off <<= 1) {
    int v = (t >= off) ? ts[t - off] : 0;
    __syncthreads();
    ts[t] += v;
    __syncthreads();
  }
  int ex = ts[t] - s;
#pragma unroll
  for (int i = 0; i < 32; i++) {
    eoff[base + i] = ex;
    cur[base + i] = ex;
    ex += vals[i];
  }
  if (t == 255) eoff[8192] = ex;
}

// ---------------- permute ----------------
__global__ __launch_bounds__(256) void k_perm(const int* __restrict__ v_ids,
                                              const int* __restrict__ e_ids,
                                              int* __restrict__ cur,
                                              int* __restrict__ perm) {
  int base = blockIdx.x * 1024 + threadIdx.x;
#pragma unroll
  for (int k = 0; k < 4; k++) {
    int i = base + k * 256;
    int e = e_ids[i];
    int v = v_ids[i];
    int pos = atomicAdd(&cur[e], 1);
    perm[pos] = v;
  }
}

// ---------------- per-edge gather-mean -> Xe (row-major) + XeTc (chunk-major) ----------------
__global__ __launch_bounds__(256) void k_gather(const u16* __restrict__ Xb,
                                                const int* __restrict__ perm,
                                                const int* __restrict__ eoff,
                                                u16* __restrict__ Xe,
                                                u16* __restrict__ XeTc) {
  __shared__ float red[4][256];
  int e = blockIdx.x;
  int tid = threadIdx.x, wave = tid >> 6, lane = tid & 63;
  int start = eoff[e], end = eoff[e + 1];
  f32x4 acc = {0.f, 0.f, 0.f, 0.f};
  for (int j = start + wave; j < end; j += 4) {
    int v = perm[j];
    bf16x4 x = *(const bf16x4*)(Xb + v * 256 + lane * 4);
#pragma unroll
    for (int c = 0; c < 4; c++) acc[c] += b2f((u16)x[c]);
  }
  *(f32x4*)&red[wave][lane * 4] = acc;
  __syncthreads();
  int t = tid;
  float s = red[0][t] + red[1][t] + red[2][t] + red[3][t];
  float m = s / fmaxf((float)(end - start), 1.0f);
  u16 b = f2b(m);
  Xe[e * 256 + t] = b;
  XeTc[(size_t)(e >> 3) * 2048 + t * 8 + (e & 7)] = b;
}

// ---------------- 128x128 swizzled GEMM, K=256 (BK=64 x 4 steps) ----------------
// tmode 0: out[row][ldout=768] bf16; tmode 1: KebT[col>>3][row][col&7] chunk-major.
__global__ __launch_bounds__(256) void k_gemm128(const u16* __restrict__ A,
                                                 const u16* __restrict__ Wt,
                                                 const float* __restrict__ bias,
                                                 u16* __restrict__ out,
                                                 int ldout, int tmode) {
  __shared__ u16 As[128 * 64];
  __shared__ u16 Bs[128 * 64];
  int tid = threadIdx.x;
  int wave = tid >> 6, lane = tid & 63;
  int quad = lane >> 4, l16 = lane & 15;
  int wm = wave >> 1, wn = wave & 1;
  int mtile = blockIdx.x * 128, ntile = blockIdx.y * 128;
  const u16* Ap = A + (size_t)mtile * 256;
  const u16* Bp = Wt + (size_t)ntile * 256;

  f32x4 acc[4][4];
#pragma unroll
  for (int am = 0; am < 4; am++)
#pragma unroll
    for (int bn = 0; bn < 4; bn++) acc[am][bn] = (f32x4){0.f, 0.f, 0.f, 0.f};

  for (int ks = 0; ks < 4; ks++) {
    __syncthreads();
#pragma unroll
    for (int i = 0; i < 4; i++) {
      int s = i * 256 + tid;
      int r = s >> 3, c = s & 7;
      gl_lds16(Ap + r * 256 + ks * 64 + ((c ^ (r & 7)) << 3), As + s * 8);
    }
#pragma unroll
    for (int i = 0; i < 4; i++) {
      int s = i * 256 + tid;
      int r = s >> 3, c = s & 7;
      gl_lds16(Bp + r * 256 + ks * 64 + ((c ^ (r & 7)) << 3), Bs + s * 8);
    }
    __syncthreads();
#pragma unroll
    for (int kc = 0; kc < 2; kc++) {
      bf16x8 a[4], b[4];
      int cc = kc * 4 + quad;
#pragma unroll
      for (int am = 0; am < 4; am++) {
        int rl = wm * 64 + am * 16 + l16;
        a[am] = *(const bf16x8*)(As + rl * 64 + ((cc ^ (rl & 7)) << 3));
      }
#pragma unroll
      for (int bn = 0; bn < 4; bn++) {
        int rl = wn * 64 + bn * 16 + l16;
        b[bn] = *(const bf16x8*)(Bs + rl * 64 + ((cc ^ (rl & 7)) << 3));
      }
#pragma unroll
      for (int am = 0; am < 4; am++)
#pragma unroll
        for (int bn = 0; bn < 4; bn++)
          acc[am][bn] = __builtin_amdgcn_mfma_f32_16x16x32_bf16(a[am], b[bn], acc[am][bn], 0, 0, 0);
    }
  }
#pragma unroll
  for (int am = 0; am < 4; am++)
#pragma unroll
    for (int bn = 0; bn < 4; bn++)
#pragma unroll
      for (int r = 0; r < 4; r++) {
        int row = mtile + wm * 64 + am * 16 + quad * 4 + r;
        int col = ntile + wn * 64 + bn * 16 + l16;
        u16 v = f2b(acc[am][bn][r] + bias[col]);
        if (tmode == 0) out[(size_t)row * ldout + col] = v;
        else out[(size_t)(col >> 3) * 65536 + row * 8 + (col & 7)] = v;
      }
}

// ---------------- flash partial, 32x32x16 MFMA, wave-pair design ----------------
// 512 blocks = 256 q-tiles x 2 splits; 4 waves = 2 pairs x 32 rows; Bk=64; 64 iters.
// LDS 72 KB: KeL [32c][64key][8] 32K | VLT [8kc][256ch][8] 32K | PL [2][32][64] 8K.
// Lv has 4 slices [split][kh] combined in k_comb (no in-kernel lsum reduction).
__global__ __launch_bounds__(256, 2) void k_flash(const u16* __restrict__ QKV,
                                                  const u16* __restrict__ KebT,
                                                  const u16* __restrict__ XeTc,
                                                  u16* __restrict__ Op,
                                                  float* __restrict__ Lv) {
  extern __shared__ u16 sm[];
  u16* KeL = sm;               // [32 c][64 key][8 u16]
  u16* VLT = sm + 16384;       // [8 kc][256 ch][8 u16]
  u16* PL = sm + 32768;        // [2 pair][32 row][64 key] u16, XOR-8 swizzle
  int tid = threadIdx.x;
  int wave = tid >> 6, lane = tid & 63;
  int l31 = lane & 31, half = lane >> 5;
  int pair = wave >> 1, kh = wave & 1;
  int qt = blockIdx.x & 255;
  int split = blockIdx.x >> 8;
  int rowp0 = qt * 64 + pair * 32;
  u16* PLp = PL + pair * 2048;

  bf16x8 qf[16];
#pragma unroll
  for (int ks = 0; ks < 16; ks++)
    qf[ks] = *(const bf16x8*)(QKV + (rowp0 + l31) * 768 + ks * 16 + half * 8);

  f32x16 o[4];
#pragma unroll
  for (int i = 0; i < 4; i++)
#pragma unroll
    for (int r = 0; r < 16; r++) o[i][r] = 0.f;
  float l[16];
#pragma unroll
  for (int r = 0; r < 16; r++) l[r] = 0.f;

  for (int ktl = 0; ktl < 64; ktl++) {
    int ktg = split * 64 + ktl;
    int kbase = ktg * 64;
    __syncthreads();  // prev tile fully consumed
#pragma unroll
    for (int i = 0; i < 8; i++) {
      int s = i * 256 + tid;
      int c = s >> 6, r = s & 63;
      gl_lds16(KebT + ((size_t)c * 8192 + kbase + r) * 8, KeL + s * 8);
    }
    int kb8 = ktg * 8;
#pragma unroll
    for (int i = 0; i < 8; i++) {
      int s = i * 256 + tid;
      int kc = s >> 8, ch = s & 255;
      gl_lds16(XeTc + ((size_t)(kb8 + kc) * 256 + ch) * 8, VLT + s * 8);
    }
    __syncthreads();  // tiles resident

    f32x16 sc;
#pragma unroll
    for (int r = 0; r < 16; r++) sc[r] = 0.f;
#pragma unroll
    for (int ks = 0; ks < 16; ks++) {
      int c = ks * 2 + half;
      bf16x8 kb = *(const bf16x8*)(KeL + c * 512 + (kh * 32 + l31) * 8);
      sc = __builtin_amdgcn_mfma_f32_32x32x16_bf16(qf[ks], kb, sc, 0, 0, 0);
    }
#pragma unroll
    for (int reg = 0; reg < 16; reg++) {
      float pv = __builtin_amdgcn_exp2f(sc[reg] * C1EXP);
      l[reg] += pv;
      int row = (reg & 3) + 8 * (reg >> 2) + 4 * half;
      int col = kh * 32 + l31;
      PLp[row * 64 + (((col >> 3) ^ (row & 7)) << 3) + (col & 7)] = f2b(pv);
    }
    __syncthreads();  // P visible across the pair
    bf16x8 pf[4];
#pragma unroll
    for (int ks = 0; ks < 4; ks++) {
      int pc = ks * 2 + half;
      pf[ks] = *(const bf16x8*)(PLp + l31 * 64 + ((pc ^ (l31 & 7)) << 3));
    }
#pragma unroll
    for (int ct = 0; ct < 4; ct++) {
#pragma unroll
      for (int ks = 0; ks < 4; ks++) {
        int kc = ks * 2 + half;
        int ch = kh * 128 + ct * 32 + l31;
        bf16x8 vb = *(const bf16x8*)(VLT + kc * 2048 + ch * 8);
        o[ct] = __builtin_amdgcn_mfma_f32_32x32x16_bf16(pf[ks], vb, o[ct], 0, 0, 0);
      }
    }
  }

  // reduce row-sums across the 32 key-lanes of this wave's half
#pragma unroll
  for (int off = 1; off < 32; off <<= 1)
#pragma unroll
    for (int r = 0; r < 16; r++) l[r] += __shfl_xor(l[r], off, 64);
  if (l31 == 0) {
#pragma unroll
    for (int reg = 0; reg < 16; reg++) {
      int row = (reg & 3) + 8 * (reg >> 2) + 4 * half;
      Lv[(split * 2 + kh) * N_NODES + rowp0 + row] = l[reg];
    }
  }

  size_t obase = (size_t)split * N_NODES * 256;
#pragma unroll
  for (int ct = 0; ct < 4; ct++)
#pragma unroll
    for (int reg = 0; reg < 16; reg++) {
      int row = rowp0 + (reg & 3) + 8 * (reg >> 2) + 4 * half;
      int col = kh * 128 + ct * 32 + l31;
      Op[obase + (size_t)row * 256 + col] = f2b(o[ct][reg]);
    }
}

// ---------------- fused: node 8x8 head attention + split combine + ReLU ----------------
__global__ __launch_bounds__(256) void k_comb(const u16* __restrict__ QKV,
                                              const u16* __restrict__ Op,
                                              const float* __restrict__ Lv,
                                              float* __restrict__ out) {
  int idx = blockIdx.x * 256 + threadIdx.x;
  int n = idx >> 6, lane = idx & 63;
  int h = lane >> 3, g = lane & 7;
  const u16* base = QKV + n * 768;
  const bf16x8* qp = (const bf16x8*)(base + h * 32);
  const bf16x8* kp = (const bf16x8*)(base + 256 + g * 32);
  float s = 0.f;
#pragma unroll
  for (int t = 0; t < 4; t++) {
    bf16x8 qv = qp[t], kv = kp[t];
#pragma unroll
    for (int j = 0; j < 8; j++) s += b2f((u16)qv[j]) * b2f((u16)kv[j]);
  }
  s *= FK_SCALE;
  float mx = s;
#pragma unroll
  for (int off = 1; off < 8; off <<= 1) mx = fmaxf(mx, __shfl_xor(mx, off, 64));
  float p = __builtin_amdgcn_exp2f((s - mx) * LOG2E);
  float lsum = p;
#pragma unroll
  for (int off = 1; off < 8; off <<= 1) lsum += __shfl_xor(lsum, off, 64);
  float attn = p / lsum;
  float a4[4] = {0.f, 0.f, 0.f, 0.f};
#pragma unroll
  for (int g2 = 0; g2 < 8; g2++) {
    float a = __shfl(attn, (lane & 56) | g2, 64);
    bf16x4 vv = *(const bf16x4*)(base + 512 + g2 * 32 + g * 4);
#pragma unroll
    for (int j = 0; j < 4; j++) a4[j] += a * b2f((u16)vv[j]);
  }
  int c4 = lane * 4;
  float L = 0.f;
#pragma unroll
  for (int sl = 0; sl < 4; sl++) L += Lv[sl * N_NODES + n];
  f32x4 acc = {0.f, 0.f, 0.f, 0.f};
#pragma unroll
  for (int sp = 0; sp < 2; sp++) {
    u16x4 ov = *(const u16x4*)(Op + (size_t)sp * N_NODES * 256 + (size_t)n * 256 + c4);
    acc.x += b2f(ov.x);
    acc.y += b2f(ov.y);
    acc.z += b2f(ov.z);
    acc.w += b2f(ov.w);
  }
  float invL = 1.0f / L;
  f32x4 res;
  res.x = fmaxf(acc.x * invL + a4[0], 0.f);
  res.y = fmaxf(acc.y * invL + a4[1], 0.f);
  res.z = fmaxf(acc.z * invL + a4[2], 0.f);
  res.w = fmaxf(acc.w * invL + a4[3], 0.f);
  *(f32x4*)(out + (size_t)n * 256 + c4) = res;
}

extern "C" void kernel_launch(void* const* d_in, const int* in_sizes, int n_in,
                              void* d_out, int out_size, void* d_ws, size_t ws_size,
                              hipStream_t stream) {
  const float* X = (const float*)d_in[0];
  const int* v_ids = (const int*)d_in[1];
  const int* e_ids = (const int*)d_in[2];
  const float* Wq = (const float*)d_in[3];
  const float* bq = (const float*)d_in[4];
  const float* Wk = (const float*)d_in[5];
  const float* bk = (const float*)d_in[6];
  const float* Wv = (const float*)d_in[7];
  const float* bv = (const float*)d_in[8];
  const float* Wke = (const float*)d_in[9];
  const float* bke = (const float*)d_in[10];
  float* out = (float*)d_out;

  char* ws = (char*)d_ws;
  u16* Xb = (u16*)(ws);                       // 8 MB   [N][256] bf16
  u16* QKV = (u16*)(ws + 8388608);            // 24 MB  [N][768] bf16
  u16* Wt = (u16*)(ws + 33554432);            // 512 KB
  float* bcat = (float*)(ws + 34078720);      // 4 KB
  int* hist = (int*)(ws + 34082816);          // 32 KB
  int* eoff = (int*)(ws + 34115584);          // 36 KB
  int* cur = (int*)(ws + 34152448);           // 32 KB
  int* perm = (int*)(ws + 34185216);          // 1 MB
  u16* Xe = (u16*)(ws + 35233792);            // 4 MB   [E][256]
  u16* XeTc = (u16*)(ws + 39428096);          // 4 MB   [E/8][256][8]
  u16* KebT = (u16*)(ws + 43622400);          // 4 MB   [32][E][8]
  u16* Op = (u16*)(ws + 64593920);            // 16 MB  [2][N][256] bf16
  float* Lv = (float*)(ws + 98148352);        // 256 KB [4][N]

  hipMemsetAsync(hist, 0, 32768, stream);
  k_prep<<<4096, 256, 0, stream>>>(X, e_ids, Xb, hist);
  k_wt<<<dim3(4, 4, 4), 256, 0, stream>>>(Wq, Wk, Wv, Wke, bq, bk, bv, bke, Wt, bcat);
  k_scan<<<1, 256, 0, stream>>>(hist, eoff, cur);
  k_perm<<<256, 256, 0, stream>>>(v_ids, e_ids, cur, perm);
  k_gather<<<8192, 256, 0, stream>>>(Xb, perm, eoff, Xe, XeTc);
  k_gemm128<<<dim3(128, 6), 256, 0, stream>>>(Xb, Wt, bcat, QKV, 768, 0);
  k_gemm128<<<dim3(64, 2), 256, 0, stream>>>(Xe, Wt + 3 * 65536, bcat + 768, KebT, 0, 1);
  hipFuncSetAttribute((const void*)k_flash, hipFuncAttributeMaxDynamicSharedMemorySize,
                      73728);
  k_flash<<<512, 256, 73728, stream>>>(QKV, KebT, XeTc, Op, Lv);
  k_comb<<<4096, 256, 0, stream>>>(QKV, Op, Lv, out);
}

// Round 12
// 350.767 us; speedup vs baseline: 2.4607x; 1.0457x over previous
//
#include <hip/hip_runtime.h>

typedef unsigned short u16;
typedef unsigned int u32;
typedef __attribute__((ext_vector_type(4))) float f32x4;
typedef __attribute__((ext_vector_type(16))) float f32x16;
typedef __attribute__((ext_vector_type(8))) short bf16x8;
typedef __attribute__((ext_vector_type(4))) short bf16x4;
typedef __attribute__((ext_vector_type(4))) u16 u16x4;

#define N_NODES 16384
#define N_EDGES 8192
#define FK_SCALE 0.17677669529663687f
#define LOG2E 1.4426950408889634f
#define C1EXP (FK_SCALE * LOG2E)

typedef const u32 __attribute__((address_space(1))) gu32;
typedef u32 __attribute__((address_space(3))) lu32;

__device__ __forceinline__ void gl_lds16(const void* g, void* l) {
  __builtin_amdgcn_global_load_lds((gu32*)g, (lu32*)l, 16, 0, 0);
}

__device__ __forceinline__ float b2f(u16 u) {
  return __builtin_bit_cast(float, (u32)u << 16);
}
__device__ __forceinline__ u16 f2b(float f) {
  u32 u = __builtin_bit_cast(u32, f);
  u += 0x7fffu + ((u >> 16) & 1u);
  return (u16)(u >> 16);
}

// ---------------- fused: X->bf16 + e_ids histogram (blocks 0..4095)
//                  + W transpose/cvt + bias pack (blocks 4096..4159) ----------------
__global__ __launch_bounds__(256) void k_prep(const float* __restrict__ X,
                                              const int* __restrict__ e_ids,
                                              u16* __restrict__ Xb,
                                              int* __restrict__ hist,
                                              const float* __restrict__ Wq,
                                              const float* __restrict__ Wk,
                                              const float* __restrict__ Wv,
                                              const float* __restrict__ Wke,
                                              const float* __restrict__ bq,
                                              const float* __restrict__ bk,
                                              const float* __restrict__ bv,
                                              const float* __restrict__ bke,
                                              u16* __restrict__ Wt,
                                              float* __restrict__ bcat) {
  __shared__ float tile[64][65];
  int b = blockIdx.x;
  int tid = threadIdx.x;
  if (b < 4096) {
    int i = b * 256 + tid;
    f32x4 v = *(const f32x4*)(X + (size_t)i * 4);
    u16x4 r;
    r.x = f2b(v.x); r.y = f2b(v.y); r.z = f2b(v.z); r.w = f2b(v.w);
    *(u16x4*)(Xb + (size_t)i * 4) = r;
    if (tid < 64) atomicAdd(&hist[e_ids[b * 64 + tid]], 1);
    return;
  }
  int local = b - 4096;
  int w = local >> 4, rem = local & 15;
  int k0 = (rem >> 2) * 64, n0 = (rem & 3) * 64;
  const float* W = (w == 0) ? Wq : (w == 1) ? Wk : (w == 2) ? Wv : Wke;
  if (rem == 0) {
    const float* bb = (w == 0) ? bq : (w == 1) ? bk : (w == 2) ? bv : bke;
    bcat[w * 256 + tid] = bb[tid];
  }
#pragma unroll
  for (int i = 0; i < 16; i++) {
    int idx = i * 256 + tid;
    int kr = idx >> 6, nc = idx & 63;
    tile[nc][kr] = W[(k0 + kr) * 256 + n0 + nc];
  }
  __syncthreads();
#pragma unroll
  for (int i = 0; i < 16; i++) {
    int idx = i * 256 + tid;
    int nr = idx >> 6, kc = idx & 63;
    Wt[w * 65536 + (n0 + nr) * 256 + k0 + kc] = f2b(tile[nr][kc]);
  }
}

// ---------------- exclusive scan (1 block) ----------------
__global__ __launch_bounds__(256) void k_scan(const int* __restrict__ hist,
                                              int* __restrict__ eoff,
                                              int* __restrict__ cur) {
  __shared__ int ts[256];
  int t = threadIdx.x;
  int base = t * 32;
  int vals[32];
  int s = 0;
#pragma unroll
  for (int i = 0; i < 32; i++) { vals[i] = hist[base + i]; s += vals[i]; }
  ts[t] = s;
  __syncthreads();
  for (int off = 1; off < 256; off <<= 1) {
    int v = (t >= off) ? ts[t - off] : 0;
    __syncthreads();
    ts[t] += v;
    __syncthreads();
  }
  int ex = ts[t] - s;
#pragma unroll
  for (int i = 0; i < 32; i++) {
    eoff[base + i] = ex;
    cur[base + i] = ex;
    ex += vals[i];
  }
  if (t == 255) eoff[8192] = ex;
}

// ---------------- permute ----------------
__global__ __launch_bounds__(256) void k_perm(const int* __restrict__ v_ids,
                                              const int* __restrict__ e_ids,
                                              int* __restrict__ cur,
                                              int* __restrict__ perm) {
  int base = blockIdx.x * 1024 + threadIdx.x;
#pragma unroll
  for (int k = 0; k < 4; k++) {
    int i = base + k * 256;
    int e = e_ids[i];
    int v = v_ids[i];
    int pos = atomicAdd(&cur[e], 1);
    perm[pos] = v;
  }
}

// ---------------- per-edge gather-mean, wave-per-edge ----------------
__global__ __launch_bounds__(256) void k_gather(const u16* __restrict__ Xb,
                                                const int* __restrict__ perm,
                                                const int* __restrict__ eoff,
                                                u16* __restrict__ Xe,
                                                u16* __restrict__ XeTc) {
  int tid = threadIdx.x, wave = tid >> 6, lane = tid & 63;
  int e = blockIdx.x * 4 + wave;
  int start = eoff[e], end = eoff[e + 1];
  f32x4 acc = {0.f, 0.f, 0.f, 0.f};
  for (int j = start; j < end; j++) {
    int v = perm[j];
    bf16x4 x = *(const bf16x4*)(Xb + (size_t)v * 256 + lane * 4);
#pragma unroll
    for (int c = 0; c < 4; c++) acc[c] += b2f((u16)x[c]);
  }
  float inv = 1.0f / fmaxf((float)(end - start), 1.0f);
  u16x4 r;
  r.x = f2b(acc.x * inv); r.y = f2b(acc.y * inv);
  r.z = f2b(acc.z * inv); r.w = f2b(acc.w * inv);
  *(u16x4*)(Xe + (size_t)e * 256 + lane * 4) = r;
  size_t tb = (size_t)(e >> 3) * 2048 + (e & 7);
  XeTc[tb + (lane * 4 + 0) * 8] = r.x;
  XeTc[tb + (lane * 4 + 1) * 8] = r.y;
  XeTc[tb + (lane * 4 + 2) * 8] = r.z;
  XeTc[tb + (lane * 4 + 3) * 8] = r.w;
}

// ---------------- 128x128 swizzled GEMM, K=256 (BK=64 x 4 steps) ----------------
// tmode 0: out[row][ldout] bf16; tmode 1: KebT[col>>3][row][col&7] chunk-major.
__global__ __launch_bounds__(256) void k_gemm128(const u16* __restrict__ A,
                                                 const u16* __restrict__ Wt,
                                                 const float* __restrict__ bias,
                                                 u16* __restrict__ out,
                                                 int ldout, int tmode) {
  __shared__ u16 As[128 * 64];
  __shared__ u16 Bs[128 * 64];
  int tid = threadIdx.x;
  int wave = tid >> 6, lane = tid & 63;
  int quad = lane >> 4, l16 = lane & 15;
  int wm = wave >> 1, wn = wave & 1;
  int mtile = blockIdx.x * 128, ntile = blockIdx.y * 128;
  const u16* Ap = A + (size_t)mtile * 256;
  const u16* Bp = Wt + (size_t)ntile * 256;

  f32x4 acc[4][4];
#pragma unroll
  for (int am = 0; am < 4; am++)
#pragma unroll
    for (int bn = 0; bn < 4; bn++) acc[am][bn] = (f32x4){0.f, 0.f, 0.f, 0.f};

  for (int ks = 0; ks < 4; ks++) {
    __syncthreads();
#pragma unroll
    for (int i = 0; i < 4; i++) {
      int s = i * 256 + tid;
      int r = s >> 3, c = s & 7;
      gl_lds16(Ap + r * 256 + ks * 64 + ((c ^ (r & 7)) << 3), As + s * 8);
    }
#pragma unroll
    for (int i = 0; i < 4; i++) {
      int s = i * 256 + tid;
      int r = s >> 3, c = s & 7;
      gl_lds16(Bp + r * 256 + ks * 64 + ((c ^ (r & 7)) << 3), Bs + s * 8);
    }
    __syncthreads();
#pragma unroll
    for (int kc = 0; kc < 2; kc++) {
      bf16x8 a[4], b[4];
      int cc = kc * 4 + quad;
#pragma unroll
      for (int am = 0; am < 4; am++) {
        int rl = wm * 64 + am * 16 + l16;
        a[am] = *(const bf16x8*)(As + rl * 64 + ((cc ^ (rl & 7)) << 3));
      }
#pragma unroll
      for (int bn = 0; bn < 4; bn++) {
        int rl = wn * 64 + bn * 16 + l16;
        b[bn] = *(const bf16x8*)(Bs + rl * 64 + ((cc ^ (rl & 7)) << 3));
      }
#pragma unroll
      for (int am = 0; am < 4; am++)
#pragma unroll
        for (int bn = 0; bn < 4; bn++)
          acc[am][bn] = __builtin_amdgcn_mfma_f32_16x16x32_bf16(a[am], b[bn], acc[am][bn], 0, 0, 0);
    }
  }
#pragma unroll
  for (int am = 0; am < 4; am++)
#pragma unroll
    for (int bn = 0; bn < 4; bn++)
#pragma unroll
      for (int r = 0; r < 4; r++) {
        int row = mtile + wm * 64 + am * 16 + quad * 4 + r;
        int col = ntile + wn * 64 + bn * 16 + l16;
        u16 v = f2b(acc[am][bn][r] + bias[col]);
        if (tmode == 0) out[(size_t)row * ldout + col] = v;
        else out[(size_t)(col >> 3) * 65536 + row * 8 + (col & 7)] = v;
      }
}

// ---------------- flash partial, 32x32x16 MFMA, wave-pair, dual QK chains ----------------
// 512 blocks = 256 q-tiles x 2 splits; 4 waves = 2 pairs x 32 rows; Bk=64; 64 iters.
// LDS 72 KB: KeL [32c][64key][8] 32K | VLT [8kc][256ch][8] 32K | PL [2][32][64] 8K.
__global__ __launch_bounds__(256, 2) void k_flash(const u16* __restrict__ QKV,
                                                  const u16* __restrict__ KebT,
                                                  const u16* __restrict__ XeTc,
                                                  u16* __restrict__ Op,
                                                  float* __restrict__ Lv) {
  extern __shared__ u16 sm[];
  u16* KeL = sm;               // [32 c][64 key][8 u16]
  u16* VLT = sm + 16384;       // [8 kc][256 ch][8 u16]
  u16* PL = sm + 32768;        // [2 pair][32 row][64 key] u16, XOR-8 swizzle
  int tid = threadIdx.x;
  int wave = tid >> 6, lane = tid & 63;
  int l31 = lane & 31, half = lane >> 5;
  int pair = wave >> 1, kh = wave & 1;
  int qt = blockIdx.x & 255;
  int split = blockIdx.x >> 8;
  int rowp0 = qt * 64 + pair * 32;
  u16* PLp = PL + pair * 2048;

  bf16x8 qf[16];
#pragma unroll
  for (int ks = 0; ks < 16; ks++)
    qf[ks] = *(const bf16x8*)(QKV + (rowp0 + l31) * 768 + ks * 16 + half * 8);

  f32x16 o[4];
#pragma unroll
  for (int i = 0; i < 4; i++)
#pragma unroll
    for (int r = 0; r < 16; r++) o[i][r] = 0.f;
  float l[16];
#pragma unroll
  for (int r = 0; r < 16; r++) l[r] = 0.f;

  for (int ktl = 0; ktl < 64; ktl++) {
    int ktg = split * 64 + ktl;
    int kbase = ktg * 64;
    __syncthreads();  // prev tile fully consumed
#pragma unroll
    for (int i = 0; i < 8; i++) {
      int s = i * 256 + tid;
      int c = s >> 6, r = s & 63;
      gl_lds16(KebT + ((size_t)c * 8192 + kbase + r) * 8, KeL + s * 8);
    }
    int kb8 = ktg * 8;
#pragma unroll
    for (int i = 0; i < 8; i++) {
      int s = i * 256 + tid;
      int kc = s >> 8, ch = s & 255;
      gl_lds16(XeTc + ((size_t)(kb8 + kc) * 256 + ch) * 8, VLT + s * 8);
    }
    __syncthreads();  // tiles resident

    // QK^T as two independent 8-MFMA chains (ILP x2 on the dep chain)
    f32x16 sc0, sc1;
#pragma unroll
    for (int r = 0; r < 16; r++) { sc0[r] = 0.f; sc1[r] = 0.f; }
#pragma unroll
    for (int ks = 0; ks < 8; ks++) {
      int c0 = ks * 2 + half;
      int c1 = (ks + 8) * 2 + half;
      bf16x8 kb0 = *(const bf16x8*)(KeL + c0 * 512 + (kh * 32 + l31) * 8);
      bf16x8 kb1 = *(const bf16x8*)(KeL + c1 * 512 + (kh * 32 + l31) * 8);
      sc0 = __builtin_amdgcn_mfma_f32_32x32x16_bf16(qf[ks], kb0, sc0, 0, 0, 0);
      sc1 = __builtin_amdgcn_mfma_f32_32x32x16_bf16(qf[ks + 8], kb1, sc1, 0, 0, 0);
    }
#pragma unroll
    for (int reg = 0; reg < 16; reg++) {
      float pv = __builtin_amdgcn_exp2f((sc0[reg] + sc1[reg]) * C1EXP);
      l[reg] += pv;
      int row = (reg & 3) + 8 * (reg >> 2) + 4 * half;
      int col = kh * 32 + l31;
      PLp[row * 64 + (((col >> 3) ^ (row & 7)) << 3) + (col & 7)] = f2b(pv);
    }
    __syncthreads();  // P visible across the pair
    bf16x8 pf[4];
#pragma unroll
    for (int ks = 0; ks < 4; ks++) {
      int pc = ks * 2 + half;
      pf[ks] = *(const bf16x8*)(PLp + l31 * 64 + ((pc ^ (l31 & 7)) << 3));
    }
#pragma unroll
    for (int ct = 0; ct < 4; ct++) {
#pragma unroll
      for (int ks = 0; ks < 4; ks++) {
        int kc = ks * 2 + half;
        int ch = kh * 128 + ct * 32 + l31;
        bf16x8 vb = *(const bf16x8*)(VLT + kc * 2048 + ch * 8);
        o[ct] = __builtin_amdgcn_mfma_f32_32x32x16_bf16(pf[ks], vb, o[ct], 0, 0, 0);
      }
    }
  }

  // reduce row-sums across the 32 key-lanes of this wave's half
#pragma unroll
  for (int off = 1; off < 32; off <<= 1)
#pragma unroll
    for (int r = 0; r < 16; r++) l[r] += __shfl_xor(l[r], off, 64);
  if (l31 == 0) {
#pragma unroll
    for (int reg = 0; reg < 16; reg++) {
      int row = (reg & 3) + 8 * (reg >> 2) + 4 * half;
      Lv[(split * 2 + kh) * N_NODES + rowp0 + row] = l[reg];
    }
  }

  size_t obase = (size_t)split * N_NODES * 256;
#pragma unroll
  for (int ct = 0; ct < 4; ct++)
#pragma unroll
    for (int reg = 0; reg < 16; reg++) {
      int row = rowp0 + (reg & 3) + 8 * (reg >> 2) + 4 * half;
      int col = kh * 128 + ct * 32 + l31;
      Op[obase + (size_t)row * 256 + col] = f2b(o[ct][reg]);
    }
}

// ---------------- fused: node 8x8 head attention + split combine + ReLU ----------------
__global__ __launch_bounds__(256) void k_comb(const u16* __restrict__ QKV,
                                              const u16* __restrict__ Op,
                                              const float* __restrict__ Lv,
                                              float* __restrict__ out) {
  int idx = blockIdx.x * 256 + threadIdx.x;
  int n = idx >> 6, lane = idx & 63;
  int h = lane >> 3, g = lane & 7;
  const u16* base = QKV + n * 768;
  const bf16x8* qp = (const bf16x8*)(base + h * 32);
  const bf16x8* kp = (const bf16x8*)(base + 256 + g * 32);
  float s = 0.f;
#pragma unroll
  for (int t = 0; t < 4; t++) {
    bf16x8 qv = qp[t], kv = kp[t];
#pragma unroll
    for (int j = 0; j < 8; j++) s += b2f((u16)qv[j]) * b2f((u16)kv[j]);
  }
  s *= FK_SCALE;
  float mx = s;
#pragma unroll
  for (int off = 1; off < 8; off <<= 1) mx = fmaxf(mx, __shfl_xor(mx, off, 64));
  float p = __builtin_amdgcn_exp2f((s - mx) * LOG2E);
  float lsum = p;
#pragma unroll
  for (int off = 1; off < 8; off <<= 1) lsum += __shfl_xor(lsum, off, 64);
  float attn = p / lsum;
  float a4[4] = {0.f, 0.f, 0.f, 0.f};
#pragma unroll
  for (int g2 = 0; g2 < 8; g2++) {
    float a = __shfl(attn, (lane & 56) | g2, 64);
    bf16x4 vv = *(const bf16x4*)(base + 512 + g2 * 32 + g * 4);
#pragma unroll
    for (int j = 0; j < 4; j++) a4[j] += a * b2f((u16)vv[j]);
  }
  int c4 = lane * 4;
  float L = 0.f;
#pragma unroll
  for (int sl = 0; sl < 4; sl++) L += Lv[sl * N_NODES + n];
  f32x4 acc = {0.f, 0.f, 0.f, 0.f};
#pragma unroll
  for (int sp = 0; sp < 2; sp++) {
    u16x4 ov = *(const u16x4*)(Op + (size_t)sp * N_NODES * 256 + (size_t)n * 256 + c4);
    acc.x += b2f(ov.x);
    acc.y += b2f(ov.y);
    acc.z += b2f(ov.z);
    acc.w += b2f(ov.w);
  }
  float invL = 1.0f / L;
  f32x4 res;
  res.x = fmaxf(acc.x * invL + a4[0], 0.f);
  res.y = fmaxf(acc.y * invL + a4[1], 0.f);
  res.z = fmaxf(acc.z * invL + a4[2], 0.f);
  res.w = fmaxf(acc.w * invL + a4[3], 0.f);
  *(f32x4*)(out + (size_t)n * 256 + c4) = res;
}

extern "C" void kernel_launch(void* const* d_in, const int* in_sizes, int n_in,
                              void* d_out, int out_size, void* d_ws, size_t ws_size,
                              hipStream_t stream) {
  const float* X = (const float*)d_in[0];
  const int* v_ids = (const int*)d_in[1];
  const int* e_ids = (const int*)d_in[2];
  const float* Wq = (const float*)d_in[3];
  const float* bq = (const float*)d_in[4];
  const float* Wk = (const float*)d_in[5];
  const float* bk = (const float*)d_in[6];
  const float* Wv = (const float*)d_in[7];
  const float* bv = (const float*)d_in[8];
  const float* Wke = (const float*)d_in[9];
  const float* bke = (const float*)d_in[10];
  float* out = (float*)d_out;

  char* ws = (char*)d_ws;
  u16* Xb = (u16*)(ws);                       // 8 MB   [N][256] bf16
  u16* QKV = (u16*)(ws + 8388608);            // 24 MB  [N][768] bf16
  u16* Wt = (u16*)(ws + 33554432);            // 512 KB
  float* bcat = (float*)(ws + 34078720);      // 4 KB
  int* hist = (int*)(ws + 34082816);          // 32 KB
  int* eoff = (int*)(ws + 34115584);          // 36 KB
  int* cur = (int*)(ws + 34152448);           // 32 KB
  int* perm = (int*)(ws + 34185216);          // 1 MB
  u16* Xe = (u16*)(ws + 35233792);            // 4 MB   [E][256]
  u16* XeTc = (u16*)(ws + 39428096);          // 4 MB   [E/8][256][8]
  u16* KebT = (u16*)(ws + 43622400);          // 4 MB   [32][E][8]
  u16* Op = (u16*)(ws + 64593920);            // 16 MB  [2][N][256] bf16
  float* Lv = (float*)(ws + 98148352);        // 256 KB [4][N]

  hipMemsetAsync(hist, 0, 32768, stream);
  k_prep<<<4160, 256, 0, stream>>>(X, e_ids, Xb, hist, Wq, Wk, Wv, Wke,
                                   bq, bk, bv, bke, Wt, bcat);
  k_scan<<<1, 256, 0, stream>>>(hist, eoff, cur);
  k_perm<<<256, 256, 0, stream>>>(v_ids, e_ids, cur, perm);
  k_gather<<<2048, 256, 0, stream>>>(Xb, perm, eoff, Xe, XeTc);
  k_gemm128<<<dim3(128, 6), 256, 0, stream>>>(Xb, Wt, bcat, QKV, 768, 0);
  k_gemm128<<<dim3(64, 2), 256, 0, stream>>>(Xe, Wt + 3 * 65536, bcat + 768, KebT, 0, 1);
  hipFuncSetAttribute((const void*)k_flash, hipFuncAttributeMaxDynamicSharedMemorySize,
                      73728);
  k_flash<<<512, 256, 73728, stream>>>(QKV, KebT, XeTc, Op, Lv);
  k_comb<<<4096, 256, 0, stream>>>(QKV, Op, Lv, out);
}

// Round 13
// 342.145 us; speedup vs baseline: 2.5227x; 1.0252x over previous
//
#include <hip/hip_runtime.h>

typedef unsigned short u16;
typedef unsigned int u32;
typedef __attribute__((ext_vector_type(4))) float f32x4;
typedef __attribute__((ext_vector_type(16))) float f32x16;
typedef __attribute__((ext_vector_type(8))) short bf16x8;
typedef __attribute__((ext_vector_type(4))) short bf16x4;
typedef __attribute__((ext_vector_type(4))) u16 u16x4;

#define N_NODES 16384
#define N_EDGES 8192
#define FK_SCALE 0.17677669529663687f
#define LOG2E 1.4426950408889634f
#define C1EXP (FK_SCALE * LOG2E)

typedef const u32 __attribute__((address_space(1))) gu32;
typedef u32 __attribute__((address_space(3))) lu32;

__device__ __forceinline__ void gl_lds16(const void* g, void* l) {
  __builtin_amdgcn_global_load_lds((gu32*)g, (lu32*)l, 16, 0, 0);
}

__device__ __forceinline__ float b2f(u16 u) {
  return __builtin_bit_cast(float, (u32)u << 16);
}
__device__ __forceinline__ u16 f2b(float f) {
  u32 u = __builtin_bit_cast(u32, f);
  u += 0x7fffu + ((u >> 16) & 1u);
  return (u16)(u >> 16);
}

// ---------------- fused: X->bf16 + e_ids histogram (blocks 0..4095)
//                  + W transpose/cvt + bias pack (blocks 4096..4159) ----------------
__global__ __launch_bounds__(256) void k_prep(const float* __restrict__ X,
                                              const int* __restrict__ e_ids,
                                              u16* __restrict__ Xb,
                                              int* __restrict__ hist,
                                              const float* __restrict__ Wq,
                                              const float* __restrict__ Wk,
                                              const float* __restrict__ Wv,
                                              const float* __restrict__ Wke,
                                              const float* __restrict__ bq,
                                              const float* __restrict__ bk,
                                              const float* __restrict__ bv,
                                              const float* __restrict__ bke,
                                              u16* __restrict__ Wt,
                                              float* __restrict__ bcat) {
  __shared__ float tile[64][65];
  int b = blockIdx.x;
  int tid = threadIdx.x;
  if (b < 4096) {
    int i = b * 256 + tid;
    f32x4 v = *(const f32x4*)(X + (size_t)i * 4);
    u16x4 r;
    r.x = f2b(v.x); r.y = f2b(v.y); r.z = f2b(v.z); r.w = f2b(v.w);
    *(u16x4*)(Xb + (size_t)i * 4) = r;
    if (tid < 64) atomicAdd(&hist[e_ids[b * 64 + tid]], 1);
    return;
  }
  int local = b - 4096;
  int w = local >> 4, rem = local & 15;
  int k0 = (rem >> 2) * 64, n0 = (rem & 3) * 64;
  const float* W = (w == 0) ? Wq : (w == 1) ? Wk : (w == 2) ? Wv : Wke;
  if (rem == 0) {
    const float* bb = (w == 0) ? bq : (w == 1) ? bk : (w == 2) ? bv : bke;
    bcat[w * 256 + tid] = bb[tid];
  }
#pragma unroll
  for (int i = 0; i < 16; i++) {
    int idx = i * 256 + tid;
    int kr = idx >> 6, nc = idx & 63;
    tile[nc][kr] = W[(k0 + kr) * 256 + n0 + nc];
  }
  __syncthreads();
#pragma unroll
  for (int i = 0; i < 16; i++) {
    int idx = i * 256 + tid;
    int nr = idx >> 6, kc = idx & 63;
    Wt[w * 65536 + (n0 + nr) * 256 + k0 + kc] = f2b(tile[nr][kc]);
  }
}

// ---------------- exclusive scan (1 block) ----------------
__global__ __launch_bounds__(256) void k_scan(const int* __restrict__ hist,
                                              int* __restrict__ eoff,
                                              int* __restrict__ cur) {
  __shared__ int ts[256];
  int t = threadIdx.x;
  int base = t * 32;
  int vals[32];
  int s = 0;
#pragma unroll
  for (int i = 0; i < 32; i++) { vals[i] = hist[base + i]; s += vals[i]; }
  ts[t] = s;
  __syncthreads();
  for (int off = 1; off < 256; off <<= 1) {
    int v = (t >= off) ? ts[t - off] : 0;
    __syncthreads();
    ts[t] += v;
    __syncthreads();
  }
  int ex = ts[t] - s;
#pragma unroll
  for (int i = 0; i < 32; i++) {
    eoff[base + i] = ex;
    cur[base + i] = ex;
    ex += vals[i];
  }
  if (t == 255) eoff[8192] = ex;
}

// ---------------- permute ----------------
__global__ __launch_bounds__(256) void k_perm(const int* __restrict__ v_ids,
                                              const int* __restrict__ e_ids,
                                              int* __restrict__ cur,
                                              int* __restrict__ perm) {
  int base = blockIdx.x * 1024 + threadIdx.x;
#pragma unroll
  for (int k = 0; k < 4; k++) {
    int i = base + k * 256;
    int e = e_ids[i];
    int v = v_ids[i];
    int pos = atomicAdd(&cur[e], 1);
    perm[pos] = v;
  }
}

// ---------------- fused launch: gemm-QKV (blocks 0..767) + gather (768..2815) ----------------
__global__ __launch_bounds__(256) void k_gg(const u16* __restrict__ Xb,
                                            const int* __restrict__ perm,
                                            const int* __restrict__ eoff,
                                            u16* __restrict__ Xe,
                                            u16* __restrict__ XeTc,
                                            const u16* __restrict__ Wt,
                                            const float* __restrict__ bcat,
                                            u16* __restrict__ QKV) {
  __shared__ u16 As[128 * 64];
  __shared__ u16 Bs[128 * 64];
  int b = blockIdx.x;
  int tid = threadIdx.x;
  int wave = tid >> 6, lane = tid & 63;
  if (b < 768) {
    // ---- 128x128 swizzled GEMM: QKV = Xb @ Wt^T + bias ----
    int quad = lane >> 4, l16 = lane & 15;
    int wm = wave >> 1, wn = wave & 1;
    int mtile = (b & 127) * 128, ntile = (b >> 7) * 128;
    const u16* Ap = Xb + (size_t)mtile * 256;
    const u16* Bp = Wt + (size_t)ntile * 256;
    f32x4 acc[4][4];
#pragma unroll
    for (int am = 0; am < 4; am++)
#pragma unroll
      for (int bn = 0; bn < 4; bn++) acc[am][bn] = (f32x4){0.f, 0.f, 0.f, 0.f};
    for (int ks = 0; ks < 4; ks++) {
      __syncthreads();
#pragma unroll
      for (int i = 0; i < 4; i++) {
        int s = i * 256 + tid;
        int r = s >> 3, c = s & 7;
        gl_lds16(Ap + r * 256 + ks * 64 + ((c ^ (r & 7)) << 3), As + s * 8);
      }
#pragma unroll
      for (int i = 0; i < 4; i++) {
        int s = i * 256 + tid;
        int r = s >> 3, c = s & 7;
        gl_lds16(Bp + r * 256 + ks * 64 + ((c ^ (r & 7)) << 3), Bs + s * 8);
      }
      __syncthreads();
#pragma unroll
      for (int kc = 0; kc < 2; kc++) {
        bf16x8 a[4], bb[4];
        int cc = kc * 4 + quad;
#pragma unroll
        for (int am = 0; am < 4; am++) {
          int rl = wm * 64 + am * 16 + l16;
          a[am] = *(const bf16x8*)(As + rl * 64 + ((cc ^ (rl & 7)) << 3));
        }
#pragma unroll
        for (int bn = 0; bn < 4; bn++) {
          int rl = wn * 64 + bn * 16 + l16;
          bb[bn] = *(const bf16x8*)(Bs + rl * 64 + ((cc ^ (rl & 7)) << 3));
        }
#pragma unroll
        for (int am = 0; am < 4; am++)
#pragma unroll
          for (int bn = 0; bn < 4; bn++)
            acc[am][bn] = __builtin_amdgcn_mfma_f32_16x16x32_bf16(a[am], bb[bn], acc[am][bn], 0, 0, 0);
      }
    }
#pragma unroll
    for (int am = 0; am < 4; am++)
#pragma unroll
      for (int bn = 0; bn < 4; bn++)
#pragma unroll
        for (int r = 0; r < 4; r++) {
          int row = mtile + wm * 64 + am * 16 + quad * 4 + r;
          int col = ntile + wn * 64 + bn * 16 + l16;
          QKV[(size_t)row * 768 + col] = f2b(acc[am][bn][r] + bcat[col]);
        }
    return;
  }
  // ---- gather: wave-per-edge, perm indices preloaded + shfl-broadcast ----
  int e = (b - 768) * 4 + wave;
  int start = eoff[e], end = eoff[e + 1];
  int cnt = end - start;
  int pidx = 0;
  if (lane < cnt) pidx = perm[start + lane];
  f32x4 acc = {0.f, 0.f, 0.f, 0.f};
  int n1 = cnt < 64 ? cnt : 64;
  for (int j = 0; j < n1; j++) {
    int v = __shfl(pidx, j, 64);
    bf16x4 x = *(const bf16x4*)(Xb + (size_t)v * 256 + lane * 4);
#pragma unroll
    for (int c = 0; c < 4; c++) acc[c] += b2f((u16)x[c]);
  }
  for (int j = start + 64; j < end; j++) {
    int v = perm[j];
    bf16x4 x = *(const bf16x4*)(Xb + (size_t)v * 256 + lane * 4);
#pragma unroll
    for (int c = 0; c < 4; c++) acc[c] += b2f((u16)x[c]);
  }
  float inv = 1.0f / fmaxf((float)cnt, 1.0f);
  u16x4 r;
  r.x = f2b(acc.x * inv); r.y = f2b(acc.y * inv);
  r.z = f2b(acc.z * inv); r.w = f2b(acc.w * inv);
  *(u16x4*)(Xe + (size_t)e * 256 + lane * 4) = r;
  size_t tb = (size_t)(e >> 3) * 2048 + (e & 7);
  XeTc[tb + (lane * 4 + 0) * 8] = r.x;
  XeTc[tb + (lane * 4 + 1) * 8] = r.y;
  XeTc[tb + (lane * 4 + 2) * 8] = r.z;
  XeTc[tb + (lane * 4 + 3) * 8] = r.w;
}

// ---------------- 128x128 swizzled GEMM for Ke, chunk-major out ----------------
__global__ __launch_bounds__(256) void k_gemmke(const u16* __restrict__ A,
                                                const u16* __restrict__ Wt,
                                                const float* __restrict__ bias,
                                                u16* __restrict__ KebT) {
  __shared__ u16 As[128 * 64];
  __shared__ u16 Bs[128 * 64];
  int tid = threadIdx.x;
  int wave = tid >> 6, lane = tid & 63;
  int quad = lane >> 4, l16 = lane & 15;
  int wm = wave >> 1, wn = wave & 1;
  int mtile = blockIdx.x * 128, ntile = blockIdx.y * 128;
  const u16* Ap = A + (size_t)mtile * 256;
  const u16* Bp = Wt + (size_t)ntile * 256;
  f32x4 acc[4][4];
#pragma unroll
  for (int am = 0; am < 4; am++)
#pragma unroll
    for (int bn = 0; bn < 4; bn++) acc[am][bn] = (f32x4){0.f, 0.f, 0.f, 0.f};
  for (int ks = 0; ks < 4; ks++) {
    __syncthreads();
#pragma unroll
    for (int i = 0; i < 4; i++) {
      int s = i * 256 + tid;
      int r = s >> 3, c = s & 7;
      gl_lds16(Ap + r * 256 + ks * 64 + ((c ^ (r & 7)) << 3), As + s * 8);
    }
#pragma unroll
    for (int i = 0; i < 4; i++) {
      int s = i * 256 + tid;
      int r = s >> 3, c = s & 7;
      gl_lds16(Bp + r * 256 + ks * 64 + ((c ^ (r & 7)) << 3), Bs + s * 8);
    }
    __syncthreads();
#pragma unroll
    for (int kc = 0; kc < 2; kc++) {
      bf16x8 a[4], b[4];
      int cc = kc * 4 + quad;
#pragma unroll
      for (int am = 0; am < 4; am++) {
        int rl = wm * 64 + am * 16 + l16;
        a[am] = *(const bf16x8*)(As + rl * 64 + ((cc ^ (rl & 7)) << 3));
      }
#pragma unroll
      for (int bn = 0; bn < 4; bn++) {
        int rl = wn * 64 + bn * 16 + l16;
        b[bn] = *(const bf16x8*)(Bs + rl * 64 + ((cc ^ (rl & 7)) << 3));
      }
#pragma unroll
      for (int am = 0; am < 4; am++)
#pragma unroll
        for (int bn = 0; bn < 4; bn++)
          acc[am][bn] = __builtin_amdgcn_mfma_f32_16x16x32_bf16(a[am], b[bn], acc[am][bn], 0, 0, 0);
    }
  }
#pragma unroll
  for (int am = 0; am < 4; am++)
#pragma unroll
    for (int bn = 0; bn < 4; bn++)
#pragma unroll
      for (int r = 0; r < 4; r++) {
        int row = mtile + wm * 64 + am * 16 + quad * 4 + r;
        int col = ntile + wn * 64 + bn * 16 + l16;
        KebT[(size_t)(col >> 3) * 65536 + row * 8 + (col & 7)] = f2b(acc[am][bn][r] + bias[col]);
      }
}

// ---------------- flash staging helpers ----------------
__device__ __forceinline__ void stage_k(const u16* __restrict__ KebT, u16* KeL,
                                        int kbase, int tid) {
#pragma unroll
  for (int i = 0; i < 8; i++) {
    int s = i * 256 + tid;
    int c = s >> 6, r = s & 63;
    gl_lds16(KebT + ((size_t)c * 8192 + kbase + r) * 8, KeL + s * 8);
  }
}
__device__ __forceinline__ void stage_v(const u16* __restrict__ XeTc, u16* VLT,
                                        int ktg, int tid) {
  int kb8 = ktg * 8;
#pragma unroll
  for (int i = 0; i < 8; i++) {
    int s = i * 256 + tid;
    int kc = s >> 8, ch = s & 255;
    gl_lds16(XeTc + ((size_t)(kb8 + kc) * 256 + ch) * 8, VLT + s * 8);
  }
}

// ---------------- flash partial, 32x32x16, wave-pair, split staging ----------------
// 512 blocks = 256 q-tiles x 2 splits; 4 waves = 2 pairs x 32 rows; Bk=64; 64 iters.
// LDS 72 KB: KeL 32K | VLT 32K | PL 8K. Staging split across barrier intervals:
// VLT(t) staged after B1 (overlaps QK, drained by B2 before PV);
// KeL(t+1) staged after B2 (overlaps PV, drained by next B1 before QK).
__global__ __launch_bounds__(256, 2) void k_flash(const u16* __restrict__ QKV,
                                                  const u16* __restrict__ KebT,
                                                  const u16* __restrict__ XeTc,
                                                  u16* __restrict__ Op,
                                                  float* __restrict__ Lv) {
  extern __shared__ u16 sm[];
  u16* KeL = sm;               // [32 c][64 key][8 u16]
  u16* VLT = sm + 16384;       // [8 kc][256 ch][8 u16]
  u16* PL = sm + 32768;        // [2 pair][32 row][64 key] u16, XOR-8 swizzle
  int tid = threadIdx.x;
  int wave = tid >> 6, lane = tid & 63;
  int l31 = lane & 31, half = lane >> 5;
  int pair = wave >> 1, kh = wave & 1;
  int qt = blockIdx.x & 255;
  int split = blockIdx.x >> 8;
  int rowp0 = qt * 64 + pair * 32;
  u16* PLp = PL + pair * 2048;

  bf16x8 qf[16];
#pragma unroll
  for (int ks = 0; ks < 16; ks++)
    qf[ks] = *(const bf16x8*)(QKV + (rowp0 + l31) * 768 + ks * 16 + half * 8);

  f32x16 o[4];
#pragma unroll
  for (int i = 0; i < 4; i++)
#pragma unroll
    for (int r = 0; r < 16; r++) o[i][r] = 0.f;
  float l[16];
#pragma unroll
  for (int r = 0; r < 16; r++) l[r] = 0.f;

  stage_k(KebT, KeL, (split * 64) * 64, tid);

  for (int ktl = 0; ktl < 64; ktl++) {
    int ktg = split * 64 + ktl;
    __syncthreads();  // B1: KeL(t) resident; PV(t-1) reads of VLT done; pf reads done
    stage_v(XeTc, VLT, ktg, tid);

    // QK^T as two independent 8-MFMA chains
    f32x16 sc0, sc1;
#pragma unroll
    for (int r = 0; r < 16; r++) { sc0[r] = 0.f; sc1[r] = 0.f; }
#pragma unroll
    for (int ks = 0; ks < 8; ks++) {
      int c0 = ks * 2 + half;
      int c1 = (ks + 8) * 2 + half;
      bf16x8 kb0 = *(const bf16x8*)(KeL + c0 * 512 + (kh * 32 + l31) * 8);
      bf16x8 kb1 = *(const bf16x8*)(KeL + c1 * 512 + (kh * 32 + l31) * 8);
      sc0 = __builtin_amdgcn_mfma_f32_32x32x16_bf16(qf[ks], kb0, sc0, 0, 0, 0);
      sc1 = __builtin_amdgcn_mfma_f32_32x32x16_bf16(qf[ks + 8], kb1, sc1, 0, 0, 0);
    }
#pragma unroll
    for (int reg = 0; reg < 16; reg++) {
      float pv = __builtin_amdgcn_exp2f((sc0[reg] + sc1[reg]) * C1EXP);
      l[reg] += pv;
      int row = (reg & 3) + 8 * (reg >> 2) + 4 * half;
      int col = kh * 32 + l31;
      PLp[row * 64 + (((col >> 3) ^ (row & 7)) << 3) + (col & 7)] = f2b(pv);
    }
    __syncthreads();  // B2: VLT(t) resident; KeL reads done; PL(t) visible
    if (ktl + 1 < 64) stage_k(KebT, KeL, (ktg + 1) * 64, tid);

    bf16x8 pf[4];
#pragma unroll
    for (int ks = 0; ks < 4; ks++) {
      int pc = ks * 2 + half;
      pf[ks] = *(const bf16x8*)(PLp + l31 * 64 + ((pc ^ (l31 & 7)) << 3));
    }
#pragma unroll
    for (int ct = 0; ct < 4; ct++) {
#pragma unroll
      for (int ks = 0; ks < 4; ks++) {
        int kc = ks * 2 + half;
        int ch = kh * 128 + ct * 32 + l31;
        bf16x8 vb = *(const bf16x8*)(VLT + kc * 2048 + ch * 8);
        o[ct] = __builtin_amdgcn_mfma_f32_32x32x16_bf16(pf[ks], vb, o[ct], 0, 0, 0);
      }
    }
  }

  // reduce row-sums across the 32 key-lanes of this wave's half
#pragma unroll
  for (int off = 1; off < 32; off <<= 1)
#pragma unroll
    for (int r = 0; r < 16; r++) l[r] += __shfl_xor(l[r], off, 64);
  if (l31 == 0) {
#pragma unroll
    for (int reg = 0; reg < 16; reg++) {
      int row = (reg & 3) + 8 * (reg >> 2) + 4 * half;
      Lv[(split * 2 + kh) * N_NODES + rowp0 + row] = l[reg];
    }
  }

  size_t obase = (size_t)split * N_NODES * 256;
#pragma unroll
  for (int ct = 0; ct < 4; ct++)
#pragma unroll
    for (int reg = 0; reg < 16; reg++) {
      int row = rowp0 + (reg & 3) + 8 * (reg >> 2) + 4 * half;
      int col = kh * 128 + ct * 32 + l31;
      Op[obase + (size_t)row * 256 + col] = f2b(o[ct][reg]);
    }
}

// ---------------- fused: node 8x8 head attention + split combine + ReLU ----------------
__global__ __launch_bounds__(256) void k_comb(const u16* __restrict__ QKV,
                                              const u16* __restrict__ Op,
                                              const float* __restrict__ Lv,
                                              float* __restrict__ out) {
  int idx = blockIdx.x * 256 + threadIdx.x;
  int n = idx >> 6, lane = idx & 63;
  int h = lane >> 3, g = lane & 7;
  const u16* base = QKV + n * 768;
  const bf16x8* qp = (const bf16x8*)(base + h * 32);
  const bf16x8* kp = (const bf16x8*)(base + 256 + g * 32);
  float s = 0.f;
#pragma unroll
  for (int t = 0; t < 4; t++) {
    bf16x8 qv = qp[t], kv = kp[t];
#pragma unroll
    for (int j = 0; j < 8; j++) s += b2f((u16)qv[j]) * b2f((u16)kv[j]);
  }
  s *= FK_SCALE;
  float mx = s;
#pragma unroll
  for (int off = 1; off < 8; off <<= 1) mx = fmaxf(mx, __shfl_xor(mx, off, 64));
  float p = __builtin_amdgcn_exp2f((s - mx) * LOG2E);
  float lsum = p;
#pragma unroll
  for (int off = 1; off < 8; off <<= 1) lsum += __shfl_xor(lsum, off, 64);
  float attn = p / lsum;
  float a4[4] = {0.f, 0.f, 0.f, 0.f};
#pragma unroll
  for (int g2 = 0; g2 < 8; g2++) {
    float a = __shfl(attn, (lane & 56) | g2, 64);
    bf16x4 vv = *(const bf16x4*)(base + 512 + g2 * 32 + g * 4);
#pragma unroll
    for (int j = 0; j < 4; j++) a4[j] += a * b2f((u16)vv[j]);
  }
  int c4 = lane * 4;
  float L = 0.f;
#pragma unroll
  for (int sl = 0; sl < 4; sl++) L += Lv[sl * N_NODES + n];
  f32x4 acc = {0.f, 0.f, 0.f, 0.f};
#pragma unroll
  for (int sp = 0; sp < 2; sp++) {
    u16x4 ov = *(const u16x4*)(Op + (size_t)sp * N_NODES * 256 + (size_t)n * 256 + c4);
    acc.x += b2f(ov.x);
    acc.y += b2f(ov.y);
    acc.z += b2f(ov.z);
    acc.w += b2f(ov.w);
  }
  float invL = 1.0f / L;
  f32x4 res;
  res.x = fmaxf(acc.x * invL + a4[0], 0.f);
  res.y = fmaxf(acc.y * invL + a4[1], 0.f);
  res.z = fmaxf(acc.z * invL + a4[2], 0.f);
  res.w = fmaxf(acc.w * invL + a4[3], 0.f);
  *(f32x4*)(out + (size_t)n * 256 + c4) = res;
}

extern "C" void kernel_launch(void* const* d_in, const int* in_sizes, int n_in,
                              void* d_out, int out_size, void* d_ws, size_t ws_size,
                              hipStream_t stream) {
  const float* X = (const float*)d_in[0];
  const int* v_ids = (const int*)d_in[1];
  const int* e_ids = (const int*)d_in[2];
  const float* Wq = (const float*)d_in[3];
  const float* bq = (const float*)d_in[4];
  const float* Wk = (const float*)d_in[5];
  const float* bk = (const float*)d_in[6];
  const float* Wv = (const float*)d_in[7];
  const float* bv = (const float*)d_in[8];
  const float* Wke = (const float*)d_in[9];
  const float* bke = (const float*)d_in[10];
  float* out = (float*)d_out;

  char* ws = (char*)d_ws;
  u16* Xb = (u16*)(ws);                       // 8 MB   [N][256] bf16
  u16* QKV = (u16*)(ws + 8388608);            // 24 MB  [N][768] bf16
  u16* Wt = (u16*)(ws + 33554432);            // 512 KB
  float* bcat = (float*)(ws + 34078720);      // 4 KB
  int* hist = (int*)(ws + 34082816);          // 32 KB
  int* eoff = (int*)(ws + 34115584);          // 36 KB
  int* cur = (int*)(ws + 34152448);           // 32 KB
  int* perm = (int*)(ws + 34185216);          // 1 MB
  u16* Xe = (u16*)(ws + 35233792);            // 4 MB   [E][256]
  u16* XeTc = (u16*)(ws + 39428096);          // 4 MB   [E/8][256][8]
  u16* KebT = (u16*)(ws + 43622400);          // 4 MB   [32][E][8]
  u16* Op = (u16*)(ws + 64593920);            // 16 MB  [2][N][256] bf16
  float* Lv = (float*)(ws + 98148352);        // 256 KB [4][N]

  hipMemsetAsync(hist, 0, 32768, stream);
  k_prep<<<4160, 256, 0, stream>>>(X, e_ids, Xb, hist, Wq, Wk, Wv, Wke,
                                   bq, bk, bv, bke, Wt, bcat);
  k_scan<<<1, 256, 0, stream>>>(hist, eoff, cur);
  k_perm<<<256, 256, 0, stream>>>(v_ids, e_ids, cur, perm);
  k_gg<<<2816, 256, 0, stream>>>(Xb, perm, eoff, Xe, XeTc, Wt, bcat, QKV);
  k_gemmke<<<dim3(64, 2), 256, 0, stream>>>(Xe, Wt + 3 * 65536, bcat + 768, KebT);
  hipFuncSetAttribute((const void*)k_flash, hipFuncAttributeMaxDynamicSharedMemorySize,
                      73728);
  k_flash<<<512, 256, 73728, stream>>>(QKV, KebT, XeTc, Op, Lv);
  k_comb<<<4096, 256, 0, stream>>>(QKV, Op, Lv, out);
}